// Round 4
// baseline (3387.606 us; speedup 1.0000x reference)
//
#include <hip/hip_runtime.h>
#include <hip/hip_bf16.h>

#define BB 256
#define CC 64
#define TT 40
#define DD 2560   // CC*TT
#define V1 25
#define V2 10
#define INTER 16
#define NH 8
#define DSH 320   // DD/NH

typedef __hip_bfloat16 bf16;
__device__ __forceinline__ float b2f(bf16 x) { return __bfloat162float(x); }

// ---------------------------------------------------------------------------
// gcn_S: block (b, subset s). X fp32 in (B, V, D) layout (K input or O).
// x[b,c,t,v] = X[b, v, c*40+t].
// M[v,v'] = sum_{j,t} a[j,t,v]*b[j,t,v'], a = Wa@x+ba, b = Wb@x+bb.
// S = softmax(M/(16*40), over v) + PA  ->  Sout (B, 3, V, V) fp32.
// ---------------------------------------------------------------------------
template<int V, int TC>
__global__ __launch_bounds__(256) void gcn_S(const float* __restrict__ X,
                                             const float* __restrict__ Wa,
                                             const float* __restrict__ ba,
                                             const float* __restrict__ Wb,
                                             const float* __restrict__ bb,
                                             const float* __restrict__ PA,
                                             float* __restrict__ Sout) {
    int b = blockIdx.x, s = blockIdx.y, tid = threadIdx.x;
    __shared__ float w[2][INTER][CC];
    __shared__ float bias[2][INTER];
    __shared__ float M[V * V];
    __shared__ float xs[CC * TC * V];           // [(c*TC+tl)*V + v]
    __shared__ float ab[2][INTER * TC * V];

    for (int e = tid; e < INTER * CC; e += 256) {
        w[0][e / CC][e % CC] = Wa[s * INTER * CC + e];
        w[1][e / CC][e % CC] = Wb[s * INTER * CC + e];
    }
    if (tid < INTER) {
        bias[0][tid] = ba[s * INTER + tid];
        bias[1][tid] = bb[s * INTER + tid];
    }
    for (int e = tid; e < V * V; e += 256) M[e] = 0.f;
    __syncthreads();

    const float* Xb = X + (size_t)b * V * DD;
    for (int tc = 0; tc < TT / TC; ++tc) {
        int t0 = tc * TC;
        for (int e = tid; e < V * CC * TC; e += 256) {
            int v = e / (CC * TC), r = e % (CC * TC);
            int c = r / TC, tl = r % TC;
            xs[(c * TC + tl) * V + v] = Xb[(size_t)v * DD + c * TT + t0 + tl];
        }
        __syncthreads();
        for (int e = tid; e < 2 * INTER * TC * V; e += 256) {
            int m = e / (INTER * TC * V), r = e % (INTER * TC * V);
            int j = r / (TC * V), p = r % (TC * V);
            float acc = bias[m][j];
            const float* wr = w[m][j];
            #pragma unroll
            for (int c = 0; c < CC; ++c) acc += xs[c * TC * V + p] * wr[c];
            ab[m][r] = acc;
        }
        __syncthreads();
        for (int e = tid; e < V * V; e += 256) {
            int v = e / V, vp = e % V;
            float acc = 0.f;
            for (int j = 0; j < INTER; ++j) {
                #pragma unroll
                for (int tl = 0; tl < TC; ++tl)
                    acc += ab[0][j * TC * V + tl * V + v] *
                           ab[1][j * TC * V + tl * V + vp];
            }
            M[e] += acc;
        }
        __syncthreads();
    }

    // softmax over v (axis=-2) per column vp, then + PA
    const float invIT = 1.0f / (float)(INTER * TT);
    for (int vp = tid; vp < V; vp += 256) {
        float mx = -1e30f;
        for (int v = 0; v < V; ++v) mx = fmaxf(mx, M[v * V + vp]);
        float sum = 0.f;
        for (int v = 0; v < V; ++v) sum += expf((M[v * V + vp] - mx) * invIT);
        float rsum = 1.0f / sum;
        for (int v = 0; v < V; ++v) {
            float e_ = expf((M[v * V + vp] - mx) * invIT);
            Sout[((size_t)(b * 3 + s) * V + v) * V + vp] =
                e_ * rsum + PA[(s * V + v) * V + vp];
        }
    }
}

// ---------------------------------------------------------------------------
// gcn_apply: y = sum_i Wd_i @ (X @ S_i) + bd_i; y = y*bnscale+bnbias + x; relu.
// X fp32 (B, V, D).  MODE 0: out_bf[b,v,ct] = y (bf16, (B,V,D), for Kg/Vg).
// MODE 1: out_f[b,v,ct] = Obuf[b,v,ct] + y (fp32, final output).
// ---------------------------------------------------------------------------
template<int V, int TC, int MODE>
__global__ __launch_bounds__(256) void gcn_apply(const float* __restrict__ X,
                                                 const float* __restrict__ Sbuf,
                                                 const float* __restrict__ Wd,
                                                 const float* __restrict__ bd,
                                                 const float* __restrict__ gamma,
                                                 const float* __restrict__ beta,
                                                 bf16* __restrict__ out_bf,
                                                 float* __restrict__ out_f,
                                                 const float* __restrict__ Obuf) {
    constexpr int CNT = CC * TC * V;
    constexpr int NPT = (CNT + 255) / 256;
    int b = blockIdx.x, chunk = blockIdx.y, tid = threadIdx.x;
    int t0 = chunk * TC;
    __shared__ float Sl[3 * V * V];
    __shared__ float wd[CC * CC];
    __shared__ float xs[CNT];                   // [(c*TC+tl)*V + v]
    __shared__ float zs[CNT];
    __shared__ float bdsum[CC], scl[CC], bet[CC];

    for (int e = tid; e < 3 * V * V; e += 256)
        Sl[e] = Sbuf[(size_t)b * 3 * V * V + e];
    if (tid < CC) {
        bdsum[tid] = bd[tid] + bd[CC + tid] + bd[2 * CC + tid];
        scl[tid] = gamma[tid] * rsqrtf(1.0f + 1e-5f);
        bet[tid] = beta[tid];
    }
    const float* Xb = X + (size_t)b * V * DD;
    for (int e = tid; e < CNT; e += 256) {
        int v = e / (CC * TC), r = e % (CC * TC);
        int c = r / TC, tl = r % TC;
        xs[(c * TC + tl) * V + v] = Xb[(size_t)v * DD + c * TT + t0 + tl];
    }
    __syncthreads();

    float acc[NPT];
    #pragma unroll
    for (int k = 0; k < NPT; ++k) acc[k] = 0.f;

    for (int s = 0; s < 3; ++s) {
        for (int e = tid; e < CC * CC; e += 256) wd[e] = Wd[s * CC * CC + e];
        __syncthreads();
        // z = X @ S_s (over v)
        for (int e = tid; e < CNT; e += 256) {
            int cp = e / (TC * V), p = e % (TC * V);
            int vp = p % V;
            int base = cp * TC * V + (p / V) * V;
            float zv = 0.f;
            #pragma unroll
            for (int v = 0; v < V; ++v)
                zv += xs[base + v] * Sl[s * V * V + v * V + vp];
            zs[e] = zv;
        }
        __syncthreads();
        // y += Wd_s @ z (over c')
        #pragma unroll
        for (int k = 0; k < NPT; ++k) {
            int e = tid + k * 256;
            if (e < CNT) {
                int c = e / (TC * V), p = e % (TC * V);
                const float* wr = &wd[c * CC];
                float a = acc[k];
                #pragma unroll
                for (int cp = 0; cp < CC; ++cp)
                    a += wr[cp] * zs[cp * TC * V + p];
                acc[k] = a;
            }
        }
        __syncthreads();
    }

    #pragma unroll
    for (int k = 0; k < NPT; ++k) {
        int e = tid + k * 256;
        if (e < CNT) {
            int c = e / (TC * V), p = e % (TC * V);
            int tl = p / V, v = p % V;
            float yv = (acc[k] + bdsum[c]) * scl[c] + bet[c] + xs[e];
            yv = fmaxf(yv, 0.f);
            size_t oi = (size_t)b * V * DD + (size_t)v * DD + c * TT + t0 + tl;
            if (MODE == 0) {
                out_bf[oi] = __float2bfloat16(yv);
            } else {
                out_f[oi] = Obuf[oi] + yv;
            }
        }
    }
}

// ---------------------------------------------------------------------------
// attention: block (b, h). Q fp32 (B,10,2560); Kg/Vg bf16 (B,25,2560).
// O[b,q,h*320+d] = Qh + sum_k softmax(QK/sqrt(2560))[q,k] * Vh[k,d]  (fp32)
// ---------------------------------------------------------------------------
__global__ __launch_bounds__(256) void attn_kernel(const float* __restrict__ Q,
                                                   const bf16* __restrict__ Kg,
                                                   const bf16* __restrict__ Vg,
                                                   float* __restrict__ O) {
    int b = blockIdx.x, h = blockIdx.y, tid = threadIdx.x;
    __shared__ float qs[10 * DSH];
    __shared__ float ks[V1 * 321];
    __shared__ float att[10 * V1];
    const float* Qb = Q + (size_t)b * 10 * DD + h * DSH;
    for (int e = tid; e < 10 * DSH; e += 256) {
        int q = e / DSH, d = e % DSH;
        qs[e] = Qb[(size_t)q * DD + d];
    }
    const bf16* Kb = Kg + (size_t)b * V1 * DD + h * DSH;
    for (int e = tid; e < V1 * DSH; e += 256) {
        int kk = e / DSH, d = e % DSH;
        ks[kk * 321 + d] = b2f(Kb[(size_t)kk * DD + d]);
    }
    __syncthreads();
    const float scale = 0.019764235376052370f;  // 1/sqrt(2560)
    for (int e = tid; e < 10 * V1; e += 256) {
        int q = e / V1, kk = e % V1;
        float acc = 0.f;
        #pragma unroll 8
        for (int d = 0; d < DSH; ++d) acc += qs[q * DSH + d] * ks[kk * 321 + d];
        att[e] = acc * scale;
    }
    __syncthreads();
    if (tid < 10) {
        float mx = -1e30f;
        for (int k = 0; k < V1; ++k) mx = fmaxf(mx, att[tid * V1 + k]);
        float sum = 0.f;
        for (int k = 0; k < V1; ++k) {
            float e_ = expf(att[tid * V1 + k] - mx);
            att[tid * V1 + k] = e_;
            sum += e_;
        }
        float r = 1.0f / sum;
        for (int k = 0; k < V1; ++k) att[tid * V1 + k] *= r;
    }
    __syncthreads();
    const bf16* Vb = Vg + (size_t)b * V1 * DD + h * DSH;
    float* Ob = O + (size_t)b * 10 * DD + h * DSH;
    for (int hh = 0; hh < 2; ++hh) {
        for (int e = tid; e < V1 * 160; e += 256) {
            int kk = e / 160, dl = e % 160;
            ks[kk * 321 + dl] = b2f(Vb[(size_t)kk * DD + hh * 160 + dl]);
        }
        __syncthreads();
        for (int e = tid; e < 10 * 160; e += 256) {
            int q = e / 160, dl = e % 160;
            float acc = 0.f;
            #pragma unroll
            for (int k = 0; k < V1; ++k) acc += att[q * V1 + k] * ks[k * 321 + dl];
            Ob[(size_t)q * DD + hh * 160 + dl] = qs[q * DSH + hh * 160 + dl] + acc;
        }
        __syncthreads();
    }
}

// ---------------------------------------------------------------------------
extern "C" void kernel_launch(void* const* d_in, const int* in_sizes, int n_in,
                              void* d_out, int out_size, void* d_ws, size_t ws_size,
                              hipStream_t stream) {
    const float* Q = (const float*)d_in[0];
    const float* K = (const float*)d_in[1];
    const float* fck_PA = (const float*)d_in[2];
    const float* fck_Wa = (const float*)d_in[3];
    const float* fck_ba = (const float*)d_in[4];
    const float* fck_Wb = (const float*)d_in[5];
    const float* fck_bb = (const float*)d_in[6];
    const float* fck_Wd = (const float*)d_in[7];
    const float* fck_bd = (const float*)d_in[8];
    const float* fck_gamma = (const float*)d_in[9];
    const float* fck_beta = (const float*)d_in[10];
    const float* fcv_PA = (const float*)d_in[11];
    const float* fcv_Wa = (const float*)d_in[12];
    const float* fcv_ba = (const float*)d_in[13];
    const float* fcv_Wb = (const float*)d_in[14];
    const float* fcv_bb = (const float*)d_in[15];
    const float* fcv_Wd = (const float*)d_in[16];
    const float* fcv_bd = (const float*)d_in[17];
    const float* fcv_gamma = (const float*)d_in[18];
    const float* fcv_beta = (const float*)d_in[19];
    const float* fco_PA = (const float*)d_in[20];
    const float* fco_Wa = (const float*)d_in[21];
    const float* fco_ba = (const float*)d_in[22];
    const float* fco_Wb = (const float*)d_in[23];
    const float* fco_bb = (const float*)d_in[24];
    const float* fco_Wd = (const float*)d_in[25];
    const float* fco_bd = (const float*)d_in[26];
    const float* fco_gamma = (const float*)d_in[27];
    const float* fco_beta = (const float*)d_in[28];

    // Workspace (bytes), no overlaps, total ~95.9 MB:
    //   Kg bf16 (B,25,2560):      [0,          32,768,000)
    //   Vg bf16 (B,25,2560):      [32,768,000, 65,536,000)
    //   O  fp32 (B,10,2560):      [65,536,000, 91,750,400)
    //   S1 fp32 (B,3,25,25):      [91,750,400, 93,670,400)
    //   S2 fp32 (B,3,25,25):      [93,670,400, 95,590,400)
    //   S3 fp32 (B,3,10,10):      [95,590,400, 95,897,600)
    char* wsb = (char*)d_ws;
    bf16* Kg = (bf16*)(wsb);
    bf16* Vg = (bf16*)(wsb + 32768000);
    float* O = (float*)(wsb + 65536000);
    float* S1 = (float*)(wsb + 91750400);
    float* S2 = (float*)(wsb + 93670400);
    float* S3 = (float*)(wsb + 95590400);

    gcn_S<V1, 4><<<dim3(BB, 3), dim3(256), 0, stream>>>(
        K, fck_Wa, fck_ba, fck_Wb, fck_bb, fck_PA, S1);
    gcn_S<V1, 4><<<dim3(BB, 3), dim3(256), 0, stream>>>(
        K, fcv_Wa, fcv_ba, fcv_Wb, fcv_bb, fcv_PA, S2);

    gcn_apply<V1, 2, 0><<<dim3(BB, 20), dim3(256), 0, stream>>>(
        K, S1, fck_Wd, fck_bd, fck_gamma, fck_beta, Kg, nullptr, nullptr);
    gcn_apply<V1, 2, 0><<<dim3(BB, 20), dim3(256), 0, stream>>>(
        K, S2, fcv_Wd, fcv_bd, fcv_gamma, fcv_beta, Vg, nullptr, nullptr);

    attn_kernel<<<dim3(BB, NH), dim3(256), 0, stream>>>(Q, Kg, Vg, O);

    gcn_S<V2, 8><<<dim3(BB, 3), dim3(256), 0, stream>>>(
        O, fco_Wa, fco_ba, fco_Wb, fco_bb, fco_PA, S3);

    gcn_apply<V2, 4, 1><<<dim3(BB, 10), dim3(256), 0, stream>>>(
        O, S3, fco_Wd, fco_bd, fco_gamma, fco_beta, nullptr, (float*)d_out, O);
}

// Round 5
// 1430.663 us; speedup vs baseline: 2.3679x; 2.3679x over previous
//
#include <hip/hip_runtime.h>
#include <hip/hip_bf16.h>

#define BB 256
#define CC 64
#define TT 40
#define DD 2560   // CC*TT
#define V1 25
#define V2 10
#define INTER 16
#define NH 8
#define DSH 320   // DD/NH

typedef __hip_bfloat16 bf16;
typedef unsigned int uint;
typedef unsigned short ushort;
__device__ __forceinline__ float b2f(bf16 x) { return __bfloat162float(x); }

// bf16 bit helpers (RNE pack, shift unpack)
__device__ __forceinline__ ushort f2bb(float f) {
    uint x = __float_as_uint(f);
    uint r = x + 0x7fffu + ((x >> 16) & 1u);
    return (ushort)(r >> 16);
}
__device__ __forceinline__ float blo(uint u) { return __uint_as_float(u << 16); }
__device__ __forceinline__ float bhi(uint u) { return __uint_as_float(u & 0xffff0000u); }

// ---------------------------------------------------------------------------
// gcn_S: unchanged from round 4 (proven correct).
// ---------------------------------------------------------------------------
template<int V, int TC>
__global__ __launch_bounds__(256) void gcn_S(const float* __restrict__ X,
                                             const float* __restrict__ Wa,
                                             const float* __restrict__ ba,
                                             const float* __restrict__ Wb,
                                             const float* __restrict__ bb,
                                             const float* __restrict__ PA,
                                             float* __restrict__ Sout) {
    int b = blockIdx.x, s = blockIdx.y, tid = threadIdx.x;
    __shared__ float w[2][INTER][CC];
    __shared__ float bias[2][INTER];
    __shared__ float M[V * V];
    __shared__ float xs[CC * TC * V];           // [(c*TC+tl)*V + v]
    __shared__ float ab[2][INTER * TC * V];

    for (int e = tid; e < INTER * CC; e += 256) {
        w[0][e / CC][e % CC] = Wa[s * INTER * CC + e];
        w[1][e / CC][e % CC] = Wb[s * INTER * CC + e];
    }
    if (tid < INTER) {
        bias[0][tid] = ba[s * INTER + tid];
        bias[1][tid] = bb[s * INTER + tid];
    }
    for (int e = tid; e < V * V; e += 256) M[e] = 0.f;
    __syncthreads();

    const float* Xb = X + (size_t)b * V * DD;
    for (int tc = 0; tc < TT / TC; ++tc) {
        int t0 = tc * TC;
        for (int e = tid; e < V * CC * TC; e += 256) {
            int v = e / (CC * TC), r = e % (CC * TC);
            int c = r / TC, tl = r % TC;
            xs[(c * TC + tl) * V + v] = Xb[(size_t)v * DD + c * TT + t0 + tl];
        }
        __syncthreads();
        for (int e = tid; e < 2 * INTER * TC * V; e += 256) {
            int m = e / (INTER * TC * V), r = e % (INTER * TC * V);
            int j = r / (TC * V), p = r % (TC * V);
            float acc = bias[m][j];
            const float* wr = w[m][j];
            #pragma unroll
            for (int c = 0; c < CC; ++c) acc += xs[c * TC * V + p] * wr[c];
            ab[m][r] = acc;
        }
        __syncthreads();
        for (int e = tid; e < V * V; e += 256) {
            int v = e / V, vp = e % V;
            float acc = 0.f;
            for (int j = 0; j < INTER; ++j) {
                #pragma unroll
                for (int tl = 0; tl < TC; ++tl)
                    acc += ab[0][j * TC * V + tl * V + v] *
                           ab[1][j * TC * V + tl * V + vp];
            }
            M[e] += acc;
        }
        __syncthreads();
    }

    const float invIT = 1.0f / (float)(INTER * TT);
    for (int vp = tid; vp < V; vp += 256) {
        float mx = -1e30f;
        for (int v = 0; v < V; ++v) mx = fmaxf(mx, M[v * V + vp]);
        float sum = 0.f;
        for (int v = 0; v < V; ++v) sum += expf((M[v * V + vp] - mx) * invIT);
        float rsum = 1.0f / sum;
        for (int v = 0; v < V; ++v) {
            float e_ = expf((M[v * V + vp] - mx) * invIT);
            Sout[((size_t)(b * 3 + s) * V + v) * V + vp] =
                e_ * rsum + PA[(s * V + v) * V + vp];
        }
    }
}

// ---------------------------------------------------------------------------
// gcn_apply2: register-tiled two-stage GEMM.
// Per block (b, t-chunk of TC): Y = sum_s Wd_s @ (X @ S_s) + epilogue.
// Column index p = v*TC + tl, P = 128 (v padded to 128/TC slots; pad cols of
// Sl are zero so pad z/Y cols are zero and never stored).
// Thread (ci,pj) = (tid>>4, tid&15): owns Y rows 4ci..4ci+3, cols 8pj..8pj+7.
// V=25: TC=4, thread cols = v' in {2pj,2pj+1} x tl 0..3.
// V=10: TC=8, thread cols = v' = pj x tl 0..7.
// MODE 0: store bf16 to out_bf (B,V,2560).  MODE 1: out_f = Obuf + y (fp32).
// ---------------------------------------------------------------------------
template<int V, int TC, int MODE>
__global__ __launch_bounds__(256) void gcn_apply2(const float* __restrict__ X,
                                                  const float* __restrict__ Sbuf,
                                                  const float* __restrict__ Wd,
                                                  const float* __restrict__ bd,
                                                  const float* __restrict__ gamma,
                                                  const float* __restrict__ beta,
                                                  bf16* __restrict__ out_bf,
                                                  float* __restrict__ out_f,
                                                  const float* __restrict__ Obuf) {
    constexpr int VSLOT = 128 / TC;            // 32 (V=25) or 16 (V=10)
    constexpr int SLS = (V == 25) ? 34 : 17;   // Sl row stride (keeps b64 align)
    constexpr int ROWS = V * TC;               // 100 or 80 real xsT rows

    __shared__ ushort xsT[ROWS][68];           // [p=v*TC+tl][c], bf16
    __shared__ ushort zs[64][136];             // [c'][p], bf16
    __shared__ float wdT[64][68];              // [c'][c]
    __shared__ float Sl[3][VSLOT][SLS];        // zero-padded cols >= V
    __shared__ float bds[64], scl[64], bet[64];

    const int tid = threadIdx.x, b = blockIdx.x, chunk = blockIdx.y;
    const int ci = tid >> 4, pj = tid & 15;
    const int t0 = chunk * TC;

    for (int e = tid; e < 3 * VSLOT * SLS; e += 256) ((float*)Sl)[e] = 0.f;
    if (tid < 64) {
        bds[tid] = bd[tid] + bd[64 + tid] + bd[128 + tid];
        scl[tid] = gamma[tid] * rsqrtf(1.f + 1e-5f);
        bet[tid] = beta[tid];
    }
    __syncthreads();
    for (int e = tid; e < 3 * V * V; e += 256) {
        int s = e / (V * V), r = e % (V * V);
        Sl[s][r / V][r % V] = Sbuf[(size_t)b * 3 * V * V + e];
    }
    const float* Xb = X + (size_t)b * V * DD;
    for (int e = tid; e < V * 64 * TC; e += 256) {
        int v = e / (64 * TC), inner = e % (64 * TC);
        int c = inner / TC, tl = inner % TC;
        xsT[v * TC + tl][c] = f2bb(Xb[(size_t)v * DD + c * TT + t0 + tl]);
    }
    __syncthreads();

    float acc2[4][8];
    #pragma unroll
    for (int r = 0; r < 4; ++r)
        #pragma unroll
        for (int cc = 0; cc < 8; ++cc) acc2[r][cc] = 0.f;

    for (int s = 0; s < 3; ++s) {
        if (s) __syncthreads();   // prev GEMM-2 done reading zs/wdT
        for (int e = tid; e < 4096; e += 256) {
            int c = e >> 6, cp = e & 63;
            wdT[cp][c] = Wd[s * 4096 + e];
        }
        // ---- GEMM-1: z = X @ S_s (registers) ----
        float za[4][8];
        #pragma unroll
        for (int r = 0; r < 4; ++r)
            #pragma unroll
            for (int cc = 0; cc < 8; ++cc) za[r][cc] = 0.f;

        if constexpr (V == 25) {
            for (int v0 = 0; v0 < 25; ++v0) {
                const float2 sv = *(const float2*)&Sl[s][v0][2 * pj];
                #pragma unroll
                for (int tl = 0; tl < 4; ++tl) {
                    const uint2 u = *(const uint2*)&xsT[v0 * 4 + tl][ci * 4];
                    const float a0 = blo(u.x), a1 = bhi(u.x);
                    const float a2 = blo(u.y), a3 = bhi(u.y);
                    za[0][tl] += a0 * sv.x;  za[0][4 + tl] += a0 * sv.y;
                    za[1][tl] += a1 * sv.x;  za[1][4 + tl] += a1 * sv.y;
                    za[2][tl] += a2 * sv.x;  za[2][4 + tl] += a2 * sv.y;
                    za[3][tl] += a3 * sv.x;  za[3][4 + tl] += a3 * sv.y;
                }
            }
        } else {  // V == 10
            for (int v0 = 0; v0 < 10; ++v0) {
                const float sv = Sl[s][v0][pj];
                #pragma unroll
                for (int tl = 0; tl < 8; ++tl) {
                    const uint2 u = *(const uint2*)&xsT[v0 * 8 + tl][ci * 4];
                    za[0][tl] += blo(u.x) * sv;
                    za[1][tl] += bhi(u.x) * sv;
                    za[2][tl] += blo(u.y) * sv;
                    za[3][tl] += bhi(u.y) * sv;
                }
            }
        }
        #pragma unroll
        for (int r = 0; r < 4; ++r) {
            uint4 pk;
            pk.x = (uint)f2bb(za[r][0]) | ((uint)f2bb(za[r][1]) << 16);
            pk.y = (uint)f2bb(za[r][2]) | ((uint)f2bb(za[r][3]) << 16);
            pk.z = (uint)f2bb(za[r][4]) | ((uint)f2bb(za[r][5]) << 16);
            pk.w = (uint)f2bb(za[r][6]) | ((uint)f2bb(za[r][7]) << 16);
            *(uint4*)&zs[ci * 4 + r][pj * 8] = pk;
        }
        __syncthreads();
        // ---- GEMM-2: Y += Wd_s @ z ----
        for (int cp = 0; cp < 64; ++cp) {
            const float4 wa = *(const float4*)&wdT[cp][ci * 4];
            const uint4 zb = *(const uint4*)&zs[cp][pj * 8];
            const float wr[4] = {wa.x, wa.y, wa.z, wa.w};
            const float zc[8] = {blo(zb.x), bhi(zb.x), blo(zb.y), bhi(zb.y),
                                 blo(zb.z), bhi(zb.z), blo(zb.w), bhi(zb.w)};
            #pragma unroll
            for (int r = 0; r < 4; ++r)
                #pragma unroll
                for (int cc = 0; cc < 8; ++cc)
                    acc2[r][cc] += wr[r] * zc[cc];
        }
    }

    // ---- epilogue: BN + residual + relu ----
    #pragma unroll
    for (int cc = 0; cc < 8; ++cc) {
        const int row = pj * 8 + cc;
        float rs[4] = {0.f, 0.f, 0.f, 0.f};
        if (row < ROWS) {
            const uint2 u = *(const uint2*)&xsT[row][ci * 4];
            rs[0] = blo(u.x); rs[1] = bhi(u.x); rs[2] = blo(u.y); rs[3] = bhi(u.y);
        }
        #pragma unroll
        for (int r = 0; r < 4; ++r) {
            const int c = ci * 4 + r;
            acc2[r][cc] = fmaxf((acc2[r][cc] + bds[c]) * scl[c] + bet[c] + rs[r], 0.f);
        }
    }

    if constexpr (MODE == 0) {
        #pragma unroll
        for (int vv = 0; vv < 2; ++vv) {
            const int v = 2 * pj + vv;
            if (v < V) {
                #pragma unroll
                for (int r = 0; r < 4; ++r) {
                    const int c = ci * 4 + r;
                    const size_t base = (size_t)b * V * DD + (size_t)v * DD + c * TT + t0;
                    uint2 pk;
                    pk.x = (uint)f2bb(acc2[r][4 * vv + 0]) |
                           ((uint)f2bb(acc2[r][4 * vv + 1]) << 16);
                    pk.y = (uint)f2bb(acc2[r][4 * vv + 2]) |
                           ((uint)f2bb(acc2[r][4 * vv + 3]) << 16);
                    *(uint2*)&out_bf[base] = pk;
                }
            }
        }
    } else {
        const int v = pj;
        if (v < V) {
            #pragma unroll
            for (int r = 0; r < 4; ++r) {
                const int c = ci * 4 + r;
                const size_t base = (size_t)b * V * DD + (size_t)v * DD + c * TT + t0;
                const float4 o0 = *(const float4*)&Obuf[base];
                const float4 o1 = *(const float4*)&Obuf[base + 4];
                float4 y0, y1;
                y0.x = o0.x + acc2[r][0]; y0.y = o0.y + acc2[r][1];
                y0.z = o0.z + acc2[r][2]; y0.w = o0.w + acc2[r][3];
                y1.x = o1.x + acc2[r][4]; y1.y = o1.y + acc2[r][5];
                y1.z = o1.z + acc2[r][6]; y1.w = o1.w + acc2[r][7];
                *(float4*)&out_f[base] = y0;
                *(float4*)&out_f[base + 4] = y1;
            }
        }
    }
}

// ---------------------------------------------------------------------------
// attention: unchanged from round 4 (proven correct).
// ---------------------------------------------------------------------------
__global__ __launch_bounds__(256) void attn_kernel(const float* __restrict__ Q,
                                                   const bf16* __restrict__ Kg,
                                                   const bf16* __restrict__ Vg,
                                                   float* __restrict__ O) {
    int b = blockIdx.x, h = blockIdx.y, tid = threadIdx.x;
    __shared__ float qs[10 * DSH];
    __shared__ float ks[V1 * 321];
    __shared__ float att[10 * V1];
    const float* Qb = Q + (size_t)b * 10 * DD + h * DSH;
    for (int e = tid; e < 10 * DSH; e += 256) {
        int q = e / DSH, d = e % DSH;
        qs[e] = Qb[(size_t)q * DD + d];
    }
    const bf16* Kb = Kg + (size_t)b * V1 * DD + h * DSH;
    for (int e = tid; e < V1 * DSH; e += 256) {
        int kk = e / DSH, d = e % DSH;
        ks[kk * 321 + d] = b2f(Kb[(size_t)kk * DD + d]);
    }
    __syncthreads();
    const float scale = 0.019764235376052370f;  // 1/sqrt(2560)
    for (int e = tid; e < 10 * V1; e += 256) {
        int q = e / V1, kk = e % V1;
        float acc = 0.f;
        #pragma unroll 8
        for (int d = 0; d < DSH; ++d) acc += qs[q * DSH + d] * ks[kk * 321 + d];
        att[e] = acc * scale;
    }
    __syncthreads();
    if (tid < 10) {
        float mx = -1e30f;
        for (int k = 0; k < V1; ++k) mx = fmaxf(mx, att[tid * V1 + k]);
        float sum = 0.f;
        for (int k = 0; k < V1; ++k) {
            float e_ = expf(att[tid * V1 + k] - mx);
            att[tid * V1 + k] = e_;
            sum += e_;
        }
        float r = 1.0f / sum;
        for (int k = 0; k < V1; ++k) att[tid * V1 + k] *= r;
    }
    __syncthreads();
    const bf16* Vb = Vg + (size_t)b * V1 * DD + h * DSH;
    float* Ob = O + (size_t)b * 10 * DD + h * DSH;
    for (int hh = 0; hh < 2; ++hh) {
        for (int e = tid; e < V1 * 160; e += 256) {
            int kk = e / 160, dl = e % 160;
            ks[kk * 321 + dl] = b2f(Vb[(size_t)kk * DD + hh * 160 + dl]);
        }
        __syncthreads();
        for (int e = tid; e < 10 * 160; e += 256) {
            int q = e / 160, dl = e % 160;
            float acc = 0.f;
            #pragma unroll
            for (int k = 0; k < V1; ++k) acc += att[q * V1 + k] * ks[k * 321 + dl];
            Ob[(size_t)q * DD + hh * 160 + dl] = qs[q * DSH + hh * 160 + dl] + acc;
        }
        __syncthreads();
    }
}

// ---------------------------------------------------------------------------
extern "C" void kernel_launch(void* const* d_in, const int* in_sizes, int n_in,
                              void* d_out, int out_size, void* d_ws, size_t ws_size,
                              hipStream_t stream) {
    const float* Q = (const float*)d_in[0];
    const float* K = (const float*)d_in[1];
    const float* fck_PA = (const float*)d_in[2];
    const float* fck_Wa = (const float*)d_in[3];
    const float* fck_ba = (const float*)d_in[4];
    const float* fck_Wb = (const float*)d_in[5];
    const float* fck_bb = (const float*)d_in[6];
    const float* fck_Wd = (const float*)d_in[7];
    const float* fck_bd = (const float*)d_in[8];
    const float* fck_gamma = (const float*)d_in[9];
    const float* fck_beta = (const float*)d_in[10];
    const float* fcv_PA = (const float*)d_in[11];
    const float* fcv_Wa = (const float*)d_in[12];
    const float* fcv_ba = (const float*)d_in[13];
    const float* fcv_Wb = (const float*)d_in[14];
    const float* fcv_bb = (const float*)d_in[15];
    const float* fcv_Wd = (const float*)d_in[16];
    const float* fcv_bd = (const float*)d_in[17];
    const float* fcv_gamma = (const float*)d_in[18];
    const float* fcv_beta = (const float*)d_in[19];
    const float* fco_PA = (const float*)d_in[20];
    const float* fco_Wa = (const float*)d_in[21];
    const float* fco_ba = (const float*)d_in[22];
    const float* fco_Wb = (const float*)d_in[23];
    const float* fco_bb = (const float*)d_in[24];
    const float* fco_Wd = (const float*)d_in[25];
    const float* fco_bd = (const float*)d_in[26];
    const float* fco_gamma = (const float*)d_in[27];
    const float* fco_beta = (const float*)d_in[28];

    // Workspace (bytes), no overlaps, total ~95.9 MB (see round-4 map).
    char* wsb = (char*)d_ws;
    bf16* Kg = (bf16*)(wsb);
    bf16* Vg = (bf16*)(wsb + 32768000);
    float* O = (float*)(wsb + 65536000);
    float* S1 = (float*)(wsb + 91750400);
    float* S2 = (float*)(wsb + 93670400);
    float* S3 = (float*)(wsb + 95590400);

    gcn_S<V1, 4><<<dim3(BB, 3), dim3(256), 0, stream>>>(
        K, fck_Wa, fck_ba, fck_Wb, fck_bb, fck_PA, S1);
    gcn_S<V1, 4><<<dim3(BB, 3), dim3(256), 0, stream>>>(
        K, fcv_Wa, fcv_ba, fcv_Wb, fcv_bb, fcv_PA, S2);

    gcn_apply2<V1, 4, 0><<<dim3(BB, 10), dim3(256), 0, stream>>>(
        K, S1, fck_Wd, fck_bd, fck_gamma, fck_beta, Kg, nullptr, nullptr);
    gcn_apply2<V1, 4, 0><<<dim3(BB, 10), dim3(256), 0, stream>>>(
        K, S2, fcv_Wd, fcv_bd, fcv_gamma, fcv_beta, Vg, nullptr, nullptr);

    attn_kernel<<<dim3(BB, NH), dim3(256), 0, stream>>>(Q, Kg, Vg, O);

    gcn_S<V2, 8><<<dim3(BB, 3), dim3(256), 0, stream>>>(
        O, fco_Wa, fco_ba, fco_Wb, fco_bb, fco_PA, S3);

    gcn_apply2<V2, 8, 1><<<dim3(BB, 5), dim3(256), 0, stream>>>(
        O, S3, fco_Wd, fco_bd, fco_gamma, fco_beta, nullptr, (float*)d_out, O);
}

// Round 6
// 1096.604 us; speedup vs baseline: 3.0892x; 1.3046x over previous
//
#include <hip/hip_runtime.h>
#include <hip/hip_bf16.h>

#define BB 256
#define CC 64
#define TT 40
#define DD 2560   // CC*TT
#define V1 25
#define V2 10
#define INTER 16
#define NH 8
#define DSH 320   // DD/NH

typedef __hip_bfloat16 bf16;
typedef unsigned int uint;
typedef unsigned short ushort;
__device__ __forceinline__ float b2f(bf16 x) { return __bfloat162float(x); }

// bf16 bit helpers (RNE pack, shift unpack)
__device__ __forceinline__ ushort f2bb(float f) {
    uint x = __float_as_uint(f);
    uint r = x + 0x7fffu + ((x >> 16) & 1u);
    return (ushort)(r >> 16);
}
__device__ __forceinline__ float blo(uint u) { return __uint_as_float(u << 16); }
__device__ __forceinline__ float bhi(uint u) { return __uint_as_float(u & 0xffff0000u); }
__device__ __forceinline__ uint4 pack8(const float* a) {
    uint4 pk;
    pk.x = (uint)f2bb(a[0]) | ((uint)f2bb(a[1]) << 16);
    pk.y = (uint)f2bb(a[2]) | ((uint)f2bb(a[3]) << 16);
    pk.z = (uint)f2bb(a[4]) | ((uint)f2bb(a[5]) << 16);
    pk.w = (uint)f2bb(a[6]) | ((uint)f2bb(a[7]) << 16);
    return pk;
}

// ---------------------------------------------------------------------------
// gcn_S2: fused S computation for NP param sets sharing input X.
// Block (b, s). X fp32 (B, V, 2560); x[c,t,v] = X[b, v, c*40+t].
// Per set: a = Wa@x+ba, bt = Wb@x+bb; M[v,vp] = sum_{j,t} a[j,t,v]*bt[j,t,vp];
// S = softmax(M/640, over v) + PA.
// LDS: xs[c][v*8+tl] bf16 (TC=8 t-chunk); ab[row][v*8+tl] bf16 where
// row = np*32 + {a:0,b:16} + j; wT[c][row] bf16. Register-tiled 4x8 proj,
// b128 Gram with per-thread register M accumulation across chunks.
// ---------------------------------------------------------------------------
template<int V, int NP>
__global__ __launch_bounds__(256) void gcn_S2(
    const float* __restrict__ X,
    const float* __restrict__ Wa0, const float* __restrict__ ba0,
    const float* __restrict__ Wb0, const float* __restrict__ bb0,
    const float* __restrict__ PA0, float* __restrict__ Sout0,
    const float* __restrict__ Wa1, const float* __restrict__ ba1,
    const float* __restrict__ Wb1, const float* __restrict__ bb1,
    const float* __restrict__ PA1, float* __restrict__ Sout1) {
    constexpr int TC = 8;
    constexpr int NCH = TT / TC;            // 5
    constexpr int P = V * TC;               // 200 / 80
    constexpr int ROWS = NP * 32;           // 64 / 32
    constexpr int NRQ = ROWS / 4;           // 16 / 8
    constexpr int NC8 = P / 8;              // 25 / 10
    constexpr int NTILE = NRQ * NC8;        // 400 / 80
    constexpr int NM = NP * V * V;          // 1250 / 100
    constexpr int NMI = (NM + 255) / 256;   // 5 / 1

    __shared__ ushort xs[64][P];
    __shared__ ushort ab[ROWS][P];
    __shared__ ushort wT[64][ROWS];
    __shared__ float biasL[ROWS];
    __shared__ float M[NM];

    const int tid = threadIdx.x, b = blockIdx.x, s = blockIdx.y;

    for (int e = tid; e < 16 * 64; e += 256) {
        int c = e & 63;
        int j = e >> 6;
        wT[c][j]      = f2bb(Wa0[s * 1024 + e]);
        wT[c][16 + j] = f2bb(Wb0[s * 1024 + e]);
        if constexpr (NP == 2) {
            wT[c][32 + j] = f2bb(Wa1[s * 1024 + e]);
            wT[c][48 + j] = f2bb(Wb1[s * 1024 + e]);
        }
    }
    if (tid < 16) {
        biasL[tid]      = ba0[s * 16 + tid];
        biasL[16 + tid] = bb0[s * 16 + tid];
        if constexpr (NP == 2) {
            biasL[32 + tid] = ba1[s * 16 + tid];
            biasL[48 + tid] = bb1[s * 16 + tid];
        }
    }

    float macc[NMI];
    #pragma unroll
    for (int k = 0; k < NMI; ++k) macc[k] = 0.f;

    const float* Xb = X + (size_t)b * V * DD;
    for (int tc = 0; tc < NCH; ++tc) {
        const int t0 = tc * TC;
        // stage x chunk: 32B contiguous per (v,c), bf16-packed to xs[c][v*8+tl]
        for (int e = tid; e < V * 64; e += 256) {
            const int v = e >> 6, c = e & 63;
            const float* src = Xb + (size_t)v * DD + c * TT + t0;
            const float4 f0 = *(const float4*)src;
            const float4 f1 = *(const float4*)(src + 4);
            const float tmp[8] = {f0.x, f0.y, f0.z, f0.w, f1.x, f1.y, f1.z, f1.w};
            *(uint4*)&xs[c][v * 8] = pack8(tmp);
        }
        __syncthreads();
        // register-tiled projection: ab[4rq+r][8co..] = bias + W @ x
        for (int tau = tid; tau < NTILE; tau += 256) {
            const int rq = tau % NRQ, co = tau / NRQ;
            float acc[4][8];
            #pragma unroll
            for (int r = 0; r < 4; ++r) {
                const float bv = biasL[4 * rq + r];
                #pragma unroll
                for (int cc = 0; cc < 8; ++cc) acc[r][cc] = bv;
            }
            for (int c = 0; c < 64; ++c) {
                const uint2 wv = *(const uint2*)&wT[c][4 * rq];
                const uint4 xv = *(const uint4*)&xs[c][8 * co];
                const float w0 = blo(wv.x), w1 = bhi(wv.x);
                const float w2 = blo(wv.y), w3 = bhi(wv.y);
                const float x0 = blo(xv.x), x1 = bhi(xv.x);
                const float x2 = blo(xv.y), x3 = bhi(xv.y);
                const float x4 = blo(xv.z), x5 = bhi(xv.z);
                const float x6 = blo(xv.w), x7 = bhi(xv.w);
                acc[0][0] += w0 * x0; acc[0][1] += w0 * x1;
                acc[0][2] += w0 * x2; acc[0][3] += w0 * x3;
                acc[0][4] += w0 * x4; acc[0][5] += w0 * x5;
                acc[0][6] += w0 * x6; acc[0][7] += w0 * x7;
                acc[1][0] += w1 * x0; acc[1][1] += w1 * x1;
                acc[1][2] += w1 * x2; acc[1][3] += w1 * x3;
                acc[1][4] += w1 * x4; acc[1][5] += w1 * x5;
                acc[1][6] += w1 * x6; acc[1][7] += w1 * x7;
                acc[2][0] += w2 * x0; acc[2][1] += w2 * x1;
                acc[2][2] += w2 * x2; acc[2][3] += w2 * x3;
                acc[2][4] += w2 * x4; acc[2][5] += w2 * x5;
                acc[2][6] += w2 * x6; acc[2][7] += w2 * x7;
                acc[3][0] += w3 * x0; acc[3][1] += w3 * x1;
                acc[3][2] += w3 * x2; acc[3][3] += w3 * x3;
                acc[3][4] += w3 * x4; acc[3][5] += w3 * x5;
                acc[3][6] += w3 * x6; acc[3][7] += w3 * x7;
            }
            #pragma unroll
            for (int r = 0; r < 4; ++r)
                *(uint4*)&ab[4 * rq + r][8 * co] = pack8(acc[r]);
        }
        __syncthreads();
        // Gram: macc[(np,v,vp)] += sum_{j,tl} a*b  (b128 reads, reg acc)
        #pragma unroll
        for (int k = 0; k < NMI; ++k) {
            const int idx = tid + k * 256;
            if (idx < NM) {
                const int np = idx / (V * V), r = idx % (V * V);
                const int v = r / V, vp = r % V;
                const int ra = np * 32, rb = np * 32 + 16;
                float mm = 0.f;
                #pragma unroll
                for (int j = 0; j < 16; ++j) {
                    const uint4 av = *(const uint4*)&ab[ra + j][v * 8];
                    const uint4 bv = *(const uint4*)&ab[rb + j][vp * 8];
                    mm += blo(av.x) * blo(bv.x) + bhi(av.x) * bhi(bv.x)
                        + blo(av.y) * blo(bv.y) + bhi(av.y) * bhi(bv.y)
                        + blo(av.z) * blo(bv.z) + bhi(av.z) * bhi(bv.z)
                        + blo(av.w) * blo(bv.w) + bhi(av.w) * bhi(bv.w);
                }
                macc[k] += mm;
            }
        }
        // next chunk's staging is ordered by the post-stage sync
    }

    #pragma unroll
    for (int k = 0; k < NMI; ++k) {
        const int idx = tid + k * 256;
        if (idx < NM) M[idx] = macc[k];
    }
    __syncthreads();

    const float invIT = 1.0f / 640.0f;
    if (tid < NP * V) {
        const int np = tid / V, vp = tid % V;
        const float* Mn = &M[np * V * V];
        float mx = -1e30f;
        for (int v = 0; v < V; ++v) mx = fmaxf(mx, Mn[v * V + vp]);
        float sum = 0.f;
        for (int v = 0; v < V; ++v) sum += expf((Mn[v * V + vp] - mx) * invIT);
        const float rs = 1.f / sum;
        const float* PAn = (np == 0) ? PA0 : PA1;
        float* Sn = (np == 0) ? Sout0 : Sout1;
        for (int v = 0; v < V; ++v) {
            const float e_ = expf((Mn[v * V + vp] - mx) * invIT);
            Sn[((size_t)(b * 3 + s) * V + v) * V + vp] =
                e_ * rs + PAn[(s * V + v) * V + vp];
        }
    }
}

// ---------------------------------------------------------------------------
// gcn_apply2: register-tiled two-stage GEMM (unchanged from round 5).
// ---------------------------------------------------------------------------
template<int V, int TC, int MODE>
__global__ __launch_bounds__(256) void gcn_apply2(const float* __restrict__ X,
                                                  const float* __restrict__ Sbuf,
                                                  const float* __restrict__ Wd,
                                                  const float* __restrict__ bd,
                                                  const float* __restrict__ gamma,
                                                  const float* __restrict__ beta,
                                                  bf16* __restrict__ out_bf,
                                                  float* __restrict__ out_f,
                                                  const float* __restrict__ Obuf) {
    constexpr int VSLOT = 128 / TC;
    constexpr int SLS = (V == 25) ? 34 : 17;
    constexpr int ROWS = V * TC;

    __shared__ ushort xsT[ROWS][68];
    __shared__ ushort zs[64][136];
    __shared__ float wdT[64][68];
    __shared__ float Sl[3][VSLOT][SLS];
    __shared__ float bds[64], scl[64], bet[64];

    const int tid = threadIdx.x, b = blockIdx.x, chunk = blockIdx.y;
    const int ci = tid >> 4, pj = tid & 15;
    const int t0 = chunk * TC;

    for (int e = tid; e < 3 * VSLOT * SLS; e += 256) ((float*)Sl)[e] = 0.f;
    if (tid < 64) {
        bds[tid] = bd[tid] + bd[64 + tid] + bd[128 + tid];
        scl[tid] = gamma[tid] * rsqrtf(1.f + 1e-5f);
        bet[tid] = beta[tid];
    }
    __syncthreads();
    for (int e = tid; e < 3 * V * V; e += 256) {
        int s = e / (V * V), r = e % (V * V);
        Sl[s][r / V][r % V] = Sbuf[(size_t)b * 3 * V * V + e];
    }
    const float* Xb = X + (size_t)b * V * DD;
    for (int e = tid; e < V * 64 * TC; e += 256) {
        int v = e / (64 * TC), inner = e % (64 * TC);
        int c = inner / TC, tl = inner % TC;
        xsT[v * TC + tl][c] = f2bb(Xb[(size_t)v * DD + c * TT + t0 + tl]);
    }
    __syncthreads();

    float acc2[4][8];
    #pragma unroll
    for (int r = 0; r < 4; ++r)
        #pragma unroll
        for (int cc = 0; cc < 8; ++cc) acc2[r][cc] = 0.f;

    for (int s = 0; s < 3; ++s) {
        if (s) __syncthreads();
        for (int e = tid; e < 4096; e += 256) {
            int c = e >> 6, cp = e & 63;
            wdT[cp][c] = Wd[s * 4096 + e];
        }
        float za[4][8];
        #pragma unroll
        for (int r = 0; r < 4; ++r)
            #pragma unroll
            for (int cc = 0; cc < 8; ++cc) za[r][cc] = 0.f;

        if constexpr (V == 25) {
            for (int v0 = 0; v0 < 25; ++v0) {
                const float2 sv = *(const float2*)&Sl[s][v0][2 * pj];
                #pragma unroll
                for (int tl = 0; tl < 4; ++tl) {
                    const uint2 u = *(const uint2*)&xsT[v0 * 4 + tl][ci * 4];
                    const float a0 = blo(u.x), a1 = bhi(u.x);
                    const float a2 = blo(u.y), a3 = bhi(u.y);
                    za[0][tl] += a0 * sv.x;  za[0][4 + tl] += a0 * sv.y;
                    za[1][tl] += a1 * sv.x;  za[1][4 + tl] += a1 * sv.y;
                    za[2][tl] += a2 * sv.x;  za[2][4 + tl] += a2 * sv.y;
                    za[3][tl] += a3 * sv.x;  za[3][4 + tl] += a3 * sv.y;
                }
            }
        } else {
            for (int v0 = 0; v0 < 10; ++v0) {
                const float sv = Sl[s][v0][pj];
                #pragma unroll
                for (int tl = 0; tl < 8; ++tl) {
                    const uint2 u = *(const uint2*)&xsT[v0 * 8 + tl][ci * 4];
                    za[0][tl] += blo(u.x) * sv;
                    za[1][tl] += bhi(u.x) * sv;
                    za[2][tl] += blo(u.y) * sv;
                    za[3][tl] += bhi(u.y) * sv;
                }
            }
        }
        #pragma unroll
        for (int r = 0; r < 4; ++r)
            *(uint4*)&zs[ci * 4 + r][pj * 8] = pack8(za[r]);
        __syncthreads();
        for (int cp = 0; cp < 64; ++cp) {
            const float4 wa = *(const float4*)&wdT[cp][ci * 4];
            const uint4 zb = *(const uint4*)&zs[cp][pj * 8];
            const float wr[4] = {wa.x, wa.y, wa.z, wa.w};
            const float zc[8] = {blo(zb.x), bhi(zb.x), blo(zb.y), bhi(zb.y),
                                 blo(zb.z), bhi(zb.z), blo(zb.w), bhi(zb.w)};
            #pragma unroll
            for (int r = 0; r < 4; ++r)
                #pragma unroll
                for (int cc = 0; cc < 8; ++cc)
                    acc2[r][cc] += wr[r] * zc[cc];
        }
    }

    #pragma unroll
    for (int cc = 0; cc < 8; ++cc) {
        const int row = pj * 8 + cc;
        float rs[4] = {0.f, 0.f, 0.f, 0.f};
        if (row < ROWS) {
            const uint2 u = *(const uint2*)&xsT[row][ci * 4];
            rs[0] = blo(u.x); rs[1] = bhi(u.x); rs[2] = blo(u.y); rs[3] = bhi(u.y);
        }
        #pragma unroll
        for (int r = 0; r < 4; ++r) {
            const int c = ci * 4 + r;
            acc2[r][cc] = fmaxf((acc2[r][cc] + bds[c]) * scl[c] + bet[c] + rs[r], 0.f);
        }
    }

    if constexpr (MODE == 0) {
        #pragma unroll
        for (int vv = 0; vv < 2; ++vv) {
            const int v = 2 * pj + vv;
            if (v < V) {
                #pragma unroll
                for (int r = 0; r < 4; ++r) {
                    const int c = ci * 4 + r;
                    const size_t base = (size_t)b * V * DD + (size_t)v * DD + c * TT + t0;
                    uint2 pk;
                    pk.x = (uint)f2bb(acc2[r][4 * vv + 0]) |
                           ((uint)f2bb(acc2[r][4 * vv + 1]) << 16);
                    pk.y = (uint)f2bb(acc2[r][4 * vv + 2]) |
                           ((uint)f2bb(acc2[r][4 * vv + 3]) << 16);
                    *(uint2*)&out_bf[base] = pk;
                }
            }
        }
    } else {
        const int v = pj;
        if (v < V) {
            #pragma unroll
            for (int r = 0; r < 4; ++r) {
                const int c = ci * 4 + r;
                const size_t base = (size_t)b * V * DD + (size_t)v * DD + c * TT + t0;
                const float4 o0 = *(const float4*)&Obuf[base];
                const float4 o1 = *(const float4*)&Obuf[base + 4];
                float4 y0, y1;
                y0.x = o0.x + acc2[r][0]; y0.y = o0.y + acc2[r][1];
                y0.z = o0.z + acc2[r][2]; y0.w = o0.w + acc2[r][3];
                y1.x = o1.x + acc2[r][4]; y1.y = o1.y + acc2[r][5];
                y1.z = o1.z + acc2[r][6]; y1.w = o1.w + acc2[r][7];
                *(float4*)&out_f[base] = y0;
                *(float4*)&out_f[base + 4] = y1;
            }
        }
    }
}

// ---------------------------------------------------------------------------
// attention (unchanged from round 4).
// ---------------------------------------------------------------------------
__global__ __launch_bounds__(256) void attn_kernel(const float* __restrict__ Q,
                                                   const bf16* __restrict__ Kg,
                                                   const bf16* __restrict__ Vg,
                                                   float* __restrict__ O) {
    int b = blockIdx.x, h = blockIdx.y, tid = threadIdx.x;
    __shared__ float qs[10 * DSH];
    __shared__ float ks[V1 * 321];
    __shared__ float att[10 * V1];
    const float* Qb = Q + (size_t)b * 10 * DD + h * DSH;
    for (int e = tid; e < 10 * DSH; e += 256) {
        int q = e / DSH, d = e % DSH;
        qs[e] = Qb[(size_t)q * DD + d];
    }
    const bf16* Kb = Kg + (size_t)b * V1 * DD + h * DSH;
    for (int e = tid; e < V1 * DSH; e += 256) {
        int kk = e / DSH, d = e % DSH;
        ks[kk * 321 + d] = b2f(Kb[(size_t)kk * DD + d]);
    }
    __syncthreads();
    const float scale = 0.019764235376052370f;  // 1/sqrt(2560)
    for (int e = tid; e < 10 * V1; e += 256) {
        int q = e / V1, kk = e % V1;
        float acc = 0.f;
        #pragma unroll 8
        for (int d = 0; d < DSH; ++d) acc += qs[q * DSH + d] * ks[kk * 321 + d];
        att[e] = acc * scale;
    }
    __syncthreads();
    if (tid < 10) {
        float mx = -1e30f;
        for (int k = 0; k < V1; ++k) mx = fmaxf(mx, att[tid * V1 + k]);
        float sum = 0.f;
        for (int k = 0; k < V1; ++k) {
            float e_ = expf(att[tid * V1 + k] - mx);
            att[tid * V1 + k] = e_;
            sum += e_;
        }
        float r = 1.0f / sum;
        for (int k = 0; k < V1; ++k) att[tid * V1 + k] *= r;
    }
    __syncthreads();
    const bf16* Vb = Vg + (size_t)b * V1 * DD + h * DSH;
    float* Ob = O + (size_t)b * 10 * DD + h * DSH;
    for (int hh = 0; hh < 2; ++hh) {
        for (int e = tid; e < V1 * 160; e += 256) {
            int kk = e / 160, dl = e % 160;
            ks[kk * 321 + dl] = b2f(Vb[(size_t)kk * DD + hh * 160 + dl]);
        }
        __syncthreads();
        for (int e = tid; e < 10 * 160; e += 256) {
            int q = e / 160, dl = e % 160;
            float acc = 0.f;
            #pragma unroll
            for (int k = 0; k < V1; ++k) acc += att[q * V1 + k] * ks[k * 321 + dl];
            Ob[(size_t)q * DD + hh * 160 + dl] = qs[q * DSH + hh * 160 + dl] + acc;
        }
        __syncthreads();
    }
}

// ---------------------------------------------------------------------------
extern "C" void kernel_launch(void* const* d_in, const int* in_sizes, int n_in,
                              void* d_out, int out_size, void* d_ws, size_t ws_size,
                              hipStream_t stream) {
    const float* Q = (const float*)d_in[0];
    const float* K = (const float*)d_in[1];
    const float* fck_PA = (const float*)d_in[2];
    const float* fck_Wa = (const float*)d_in[3];
    const float* fck_ba = (const float*)d_in[4];
    const float* fck_Wb = (const float*)d_in[5];
    const float* fck_bb = (const float*)d_in[6];
    const float* fck_Wd = (const float*)d_in[7];
    const float* fck_bd = (const float*)d_in[8];
    const float* fck_gamma = (const float*)d_in[9];
    const float* fck_beta = (const float*)d_in[10];
    const float* fcv_PA = (const float*)d_in[11];
    const float* fcv_Wa = (const float*)d_in[12];
    const float* fcv_ba = (const float*)d_in[13];
    const float* fcv_Wb = (const float*)d_in[14];
    const float* fcv_bb = (const float*)d_in[15];
    const float* fcv_Wd = (const float*)d_in[16];
    const float* fcv_bd = (const float*)d_in[17];
    const float* fcv_gamma = (const float*)d_in[18];
    const float* fcv_beta = (const float*)d_in[19];
    const float* fco_PA = (const float*)d_in[20];
    const float* fco_Wa = (const float*)d_in[21];
    const float* fco_ba = (const float*)d_in[22];
    const float* fco_Wb = (const float*)d_in[23];
    const float* fco_bb = (const float*)d_in[24];
    const float* fco_Wd = (const float*)d_in[25];
    const float* fco_bd = (const float*)d_in[26];
    const float* fco_gamma = (const float*)d_in[27];
    const float* fco_beta = (const float*)d_in[28];

    // Workspace (bytes), no overlaps, total ~95.9 MB (round-4 map).
    char* wsb = (char*)d_ws;
    bf16* Kg = (bf16*)(wsb);
    bf16* Vg = (bf16*)(wsb + 32768000);
    float* O = (float*)(wsb + 65536000);
    float* S1 = (float*)(wsb + 91750400);
    float* S2 = (float*)(wsb + 93670400);
    float* S3 = (float*)(wsb + 95590400);

    gcn_S2<V1, 2><<<dim3(BB, 3), dim3(256), 0, stream>>>(
        K, fck_Wa, fck_ba, fck_Wb, fck_bb, fck_PA, S1,
        fcv_Wa, fcv_ba, fcv_Wb, fcv_bb, fcv_PA, S2);

    gcn_apply2<V1, 4, 0><<<dim3(BB, 10), dim3(256), 0, stream>>>(
        K, S1, fck_Wd, fck_bd, fck_gamma, fck_beta, Kg, nullptr, nullptr);
    gcn_apply2<V1, 4, 0><<<dim3(BB, 10), dim3(256), 0, stream>>>(
        K, S2, fcv_Wd, fcv_bd, fcv_gamma, fcv_beta, Vg, nullptr, nullptr);

    attn_kernel<<<dim3(BB, NH), dim3(256), 0, stream>>>(Q, Kg, Vg, O);

    gcn_S2<V2, 1><<<dim3(BB, 3), dim3(256), 0, stream>>>(
        O, fco_Wa, fco_ba, fco_Wb, fco_bb, fco_PA, S3,
        nullptr, nullptr, nullptr, nullptr, nullptr, nullptr);

    gcn_apply2<V2, 8, 1><<<dim3(BB, 5), dim3(256), 0, stream>>>(
        O, S3, fco_Wd, fco_bd, fco_gamma, fco_beta, nullptr, (float*)d_out, O);
}

// Round 7
// 863.161 us; speedup vs baseline: 3.9247x; 1.2705x over previous
//
#include <hip/hip_runtime.h>
#include <hip/hip_bf16.h>

#define BB 256
#define CC 64
#define TT 40
#define DD 2560   // CC*TT
#define V1 25
#define V2 10
#define INTER 16
#define NH 8
#define DSH 320   // DD/NH

typedef __hip_bfloat16 bf16;
typedef unsigned int uint;
typedef unsigned short ushort;
typedef __attribute__((ext_vector_type(8))) short bf16x8;
typedef __attribute__((ext_vector_type(4))) float f32x4;

__device__ __forceinline__ float b2f(bf16 x) { return __bfloat162float(x); }

// bf16 bit helpers (RNE pack, shift unpack)
__device__ __forceinline__ ushort f2bb(float f) {
    uint x = __float_as_uint(f);
    uint r = x + 0x7fffu + ((x >> 16) & 1u);
    return (ushort)(r >> 16);
}
__device__ __forceinline__ float blo(uint u) { return __uint_as_float(u << 16); }
__device__ __forceinline__ float bhi(uint u) { return __uint_as_float(u & 0xffff0000u); }
__device__ __forceinline__ float b2f_us(ushort h) { return __uint_as_float(((uint)h) << 16); }
__device__ __forceinline__ uint4 pack8(const float* a) {
    uint4 pk;
    pk.x = (uint)f2bb(a[0]) | ((uint)f2bb(a[1]) << 16);
    pk.y = (uint)f2bb(a[2]) | ((uint)f2bb(a[3]) << 16);
    pk.z = (uint)f2bb(a[4]) | ((uint)f2bb(a[5]) << 16);
    pk.w = (uint)f2bb(a[6]) | ((uint)f2bb(a[7]) << 16);
    return pk;
}
// 16B fragment load from an 8B-aligned (not 16B-aligned) LDS row
__device__ __forceinline__ bf16x8 ldfrag8(const ushort* p) {
    union { bf16x8 v; uint2 u[2]; } t;
    t.u[0] = *(const uint2*)p;
    t.u[1] = *(const uint2*)(p + 4);
    return t.v;
}

// ---------------------------------------------------------------------------
// gcn_S2: fused S computation for NP param sets (unchanged from round 6).
// ---------------------------------------------------------------------------
template<int V, int NP>
__global__ __launch_bounds__(256) void gcn_S2(
    const float* __restrict__ X,
    const float* __restrict__ Wa0, const float* __restrict__ ba0,
    const float* __restrict__ Wb0, const float* __restrict__ bb0,
    const float* __restrict__ PA0, float* __restrict__ Sout0,
    const float* __restrict__ Wa1, const float* __restrict__ ba1,
    const float* __restrict__ Wb1, const float* __restrict__ bb1,
    const float* __restrict__ PA1, float* __restrict__ Sout1) {
    constexpr int TC = 8;
    constexpr int NCH = TT / TC;
    constexpr int P = V * TC;
    constexpr int ROWS = NP * 32;
    constexpr int NRQ = ROWS / 4;
    constexpr int NC8 = P / 8;
    constexpr int NTILE = NRQ * NC8;
    constexpr int NM = NP * V * V;
    constexpr int NMI = (NM + 255) / 256;

    __shared__ ushort xs[64][P];
    __shared__ ushort ab[ROWS][P];
    __shared__ ushort wT[64][ROWS];
    __shared__ float biasL[ROWS];
    __shared__ float M[NM];

    const int tid = threadIdx.x, b = blockIdx.x, s = blockIdx.y;

    for (int e = tid; e < 16 * 64; e += 256) {
        int c = e & 63;
        int j = e >> 6;
        wT[c][j]      = f2bb(Wa0[s * 1024 + e]);
        wT[c][16 + j] = f2bb(Wb0[s * 1024 + e]);
        if constexpr (NP == 2) {
            wT[c][32 + j] = f2bb(Wa1[s * 1024 + e]);
            wT[c][48 + j] = f2bb(Wb1[s * 1024 + e]);
        }
    }
    if (tid < 16) {
        biasL[tid]      = ba0[s * 16 + tid];
        biasL[16 + tid] = bb0[s * 16 + tid];
        if constexpr (NP == 2) {
            biasL[32 + tid] = ba1[s * 16 + tid];
            biasL[48 + tid] = bb1[s * 16 + tid];
        }
    }

    float macc[NMI];
    #pragma unroll
    for (int k = 0; k < NMI; ++k) macc[k] = 0.f;

    const float* Xb = X + (size_t)b * V * DD;
    for (int tc = 0; tc < NCH; ++tc) {
        const int t0 = tc * TC;
        for (int e = tid; e < V * 64; e += 256) {
            const int v = e >> 6, c = e & 63;
            const float* src = Xb + (size_t)v * DD + c * TT + t0;
            const float4 f0 = *(const float4*)src;
            const float4 f1 = *(const float4*)(src + 4);
            const float tmp[8] = {f0.x, f0.y, f0.z, f0.w, f1.x, f1.y, f1.z, f1.w};
            *(uint4*)&xs[c][v * 8] = pack8(tmp);
        }
        __syncthreads();
        for (int tau = tid; tau < NTILE; tau += 256) {
            const int rq = tau % NRQ, co = tau / NRQ;
            float acc[4][8];
            #pragma unroll
            for (int r = 0; r < 4; ++r) {
                const float bv = biasL[4 * rq + r];
                #pragma unroll
                for (int cc = 0; cc < 8; ++cc) acc[r][cc] = bv;
            }
            for (int c = 0; c < 64; ++c) {
                const uint2 wv = *(const uint2*)&wT[c][4 * rq];
                const uint4 xv = *(const uint4*)&xs[c][8 * co];
                const float w0 = blo(wv.x), w1 = bhi(wv.x);
                const float w2 = blo(wv.y), w3 = bhi(wv.y);
                const float x0 = blo(xv.x), x1 = bhi(xv.x);
                const float x2 = blo(xv.y), x3 = bhi(xv.y);
                const float x4 = blo(xv.z), x5 = bhi(xv.z);
                const float x6 = blo(xv.w), x7 = bhi(xv.w);
                acc[0][0] += w0 * x0; acc[0][1] += w0 * x1;
                acc[0][2] += w0 * x2; acc[0][3] += w0 * x3;
                acc[0][4] += w0 * x4; acc[0][5] += w0 * x5;
                acc[0][6] += w0 * x6; acc[0][7] += w0 * x7;
                acc[1][0] += w1 * x0; acc[1][1] += w1 * x1;
                acc[1][2] += w1 * x2; acc[1][3] += w1 * x3;
                acc[1][4] += w1 * x4; acc[1][5] += w1 * x5;
                acc[1][6] += w1 * x6; acc[1][7] += w1 * x7;
                acc[2][0] += w2 * x0; acc[2][1] += w2 * x1;
                acc[2][2] += w2 * x2; acc[2][3] += w2 * x3;
                acc[2][4] += w2 * x4; acc[2][5] += w2 * x5;
                acc[2][6] += w2 * x6; acc[2][7] += w2 * x7;
                acc[3][0] += w3 * x0; acc[3][1] += w3 * x1;
                acc[3][2] += w3 * x2; acc[3][3] += w3 * x3;
                acc[3][4] += w3 * x4; acc[3][5] += w3 * x5;
                acc[3][6] += w3 * x6; acc[3][7] += w3 * x7;
            }
            #pragma unroll
            for (int r = 0; r < 4; ++r)
                *(uint4*)&ab[4 * rq + r][8 * co] = pack8(acc[r]);
        }
        __syncthreads();
        #pragma unroll
        for (int k = 0; k < NMI; ++k) {
            const int idx = tid + k * 256;
            if (idx < NM) {
                const int np = idx / (V * V), r = idx % (V * V);
                const int v = r / V, vp = r % V;
                const int ra = np * 32, rb = np * 32 + 16;
                float mm = 0.f;
                #pragma unroll
                for (int j = 0; j < 16; ++j) {
                    const uint4 av = *(const uint4*)&ab[ra + j][v * 8];
                    const uint4 bv = *(const uint4*)&ab[rb + j][vp * 8];
                    mm += blo(av.x) * blo(bv.x) + bhi(av.x) * bhi(bv.x)
                        + blo(av.y) * blo(bv.y) + bhi(av.y) * bhi(bv.y)
                        + blo(av.z) * blo(bv.z) + bhi(av.z) * bhi(bv.z)
                        + blo(av.w) * blo(bv.w) + bhi(av.w) * bhi(bv.w);
                }
                macc[k] += mm;
            }
        }
    }

    #pragma unroll
    for (int k = 0; k < NMI; ++k) {
        const int idx = tid + k * 256;
        if (idx < NM) M[idx] = macc[k];
    }
    __syncthreads();

    const float invIT = 1.0f / 640.0f;
    if (tid < NP * V) {
        const int np = tid / V, vp = tid % V;
        const float* Mn = &M[np * V * V];
        float mx = -1e30f;
        for (int v = 0; v < V; ++v) mx = fmaxf(mx, Mn[v * V + vp]);
        float sum = 0.f;
        for (int v = 0; v < V; ++v) sum += expf((Mn[v * V + vp] - mx) * invIT);
        const float rs = 1.f / sum;
        const float* PAn = (np == 0) ? PA0 : PA1;
        float* Sn = (np == 0) ? Sout0 : Sout1;
        for (int v = 0; v < V; ++v) {
            const float e_ = expf((Mn[v * V + vp] - mx) * invIT);
            Sn[((size_t)(b * 3 + s) * V + v) * V + vp] =
                e_ * rs + PAn[(s * V + v) * V + vp];
        }
    }
}

// ---------------------------------------------------------------------------
// gcn_apply3: register GEMM-1 (z = X@S) + MFMA GEMM-2 (Y += Wd@z).
// Per block (b, t-chunk TC). Columns p = v'*TC + tl, P = 128 (v' zero-padded).
// zsT[p][cp] bf16 (B^T layout: k=cp contiguous) feeds B-fragments; Wd staged
// [o][i] pad-72 feeds A-fragments; mfma_f32_16x16x32_bf16, wave w = m-tile.
// Epilogue: BN+residual+relu on C-frags -> ys (aliases zsT) -> coalesced store.
// MODE 0: out_bf (B,V,2560) bf16.  MODE 1: out_f = Obuf + y (fp32 final).
// ---------------------------------------------------------------------------
template<int V, int TC, int MODE>
__global__ __launch_bounds__(256) void gcn_apply3(const float* __restrict__ X,
                                                  const float* __restrict__ Sbuf,
                                                  const float* __restrict__ Wd,
                                                  const float* __restrict__ bd,
                                                  const float* __restrict__ gamma,
                                                  const float* __restrict__ beta,
                                                  bf16* __restrict__ out_bf,
                                                  float* __restrict__ out_f,
                                                  const float* __restrict__ Obuf) {
    constexpr int VSLOT = 128 / TC;            // 32 (V=25) / 16 (V=10)
    constexpr int ROWS = V * TC;               // 100 / 80 valid p's
    constexpr int NT = (V == 25) ? 7 : 5;      // n-tiles covering valid p

    __shared__ ushort xsT[ROWS][68];           // [p][c] bf16 (GEMM-1 A + residual)
    __shared__ ushort zsT[128][68];            // [p][cp] bf16; later ys[p][c]
    __shared__ ushort wdT[64][72];             // [o][i] bf16, 16B-aligned rows
    __shared__ ushort Sl[3][VSLOT][34];        // bf16, zero-padded v' slots
    __shared__ float bds[64], scl[64], bet[64];

    const int tid = threadIdx.x, b = blockIdx.x, chunk = blockIdx.y;
    const int ci = tid >> 4, pj = tid & 15;
    const int lane = tid & 63, w = tid >> 6;   // wave = m-tile (c rows w*16..)
    const int ln = lane & 15, lq = lane >> 4;
    const int t0 = chunk * TC;

    for (int e = tid; e < 3 * VSLOT * 17; e += 256) ((uint*)Sl)[e] = 0u;
    if (tid < 64) {
        bds[tid] = bd[tid] + bd[64 + tid] + bd[128 + tid];
        scl[tid] = gamma[tid] * rsqrtf(1.f + 1e-5f);
        bet[tid] = beta[tid];
    }
    __syncthreads();
    for (int e = tid; e < 3 * V * V; e += 256) {
        int s = e / (V * V), r = e % (V * V);
        Sl[s][r / V][r % V] = f2bb(Sbuf[(size_t)b * 3 * V * V + e]);
    }
    const float* Xb = X + (size_t)b * V * DD;
    for (int e = tid; e < V * 64 * TC; e += 256) {
        int v = e / (64 * TC), inner = e % (64 * TC);
        int c = inner / TC, tl = inner % TC;
        xsT[v * TC + tl][c] = f2bb(Xb[(size_t)v * DD + c * TT + t0 + tl]);
    }
    __syncthreads();

    f32x4 acc[NT];
    #pragma unroll
    for (int tn = 0; tn < NT; ++tn) acc[tn] = (f32x4){0.f, 0.f, 0.f, 0.f};

    for (int s = 0; s < 3; ++s) {
        if (s) __syncthreads();   // prior mfma done reading zsT/wdT
        for (int e = tid; e < 4096; e += 256)
            wdT[e >> 6][e & 63] = f2bb(Wd[s * 4096 + e]);

        // ---- GEMM-1 (registers): z[cp][p] = sum_v X[cp][(v,tl)] S[v][v'] ----
        float za[4][8];
        #pragma unroll
        for (int r = 0; r < 4; ++r)
            #pragma unroll
            for (int cc = 0; cc < 8; ++cc) za[r][cc] = 0.f;

        if constexpr (V == 25) {
            for (int v0 = 0; v0 < 25; ++v0) {
                const uint sv = *(const uint*)&Sl[s][v0][2 * pj];
                const float svx = blo(sv), svy = bhi(sv);
                #pragma unroll
                for (int tl = 0; tl < 4; ++tl) {
                    const uint2 u = *(const uint2*)&xsT[v0 * 4 + tl][ci * 4];
                    const float a0 = blo(u.x), a1 = bhi(u.x);
                    const float a2 = blo(u.y), a3 = bhi(u.y);
                    za[0][tl] += a0 * svx;  za[0][4 + tl] += a0 * svy;
                    za[1][tl] += a1 * svx;  za[1][4 + tl] += a1 * svy;
                    za[2][tl] += a2 * svx;  za[2][4 + tl] += a2 * svy;
                    za[3][tl] += a3 * svx;  za[3][4 + tl] += a3 * svy;
                }
            }
        } else {
            for (int v0 = 0; v0 < 10; ++v0) {
                const float sv = b2f_us(Sl[s][v0][pj]);
                #pragma unroll
                for (int tl = 0; tl < 8; ++tl) {
                    const uint2 u = *(const uint2*)&xsT[v0 * 8 + tl][ci * 4];
                    za[0][tl] += blo(u.x) * sv;
                    za[1][tl] += bhi(u.x) * sv;
                    za[2][tl] += blo(u.y) * sv;
                    za[3][tl] += bhi(u.y) * sv;
                }
            }
        }
        // store z transposed: zsT[p=pj*8+cc][cp=ci*4+r]
        #pragma unroll
        for (int cc = 0; cc < 8; ++cc) {
            uint2 pk;
            pk.x = (uint)f2bb(za[0][cc]) | ((uint)f2bb(za[1][cc]) << 16);
            pk.y = (uint)f2bb(za[2][cc]) | ((uint)f2bb(za[3][cc]) << 16);
            *(uint2*)&zsT[pj * 8 + cc][ci * 4] = pk;
        }
        __syncthreads();

        // ---- GEMM-2 (MFMA): Y[c][p] += Wd[c][cp] z[cp][p] ----
        const bf16x8 a0 = *(const bf16x8*)&wdT[w * 16 + ln][lq * 8];
        const bf16x8 a1 = *(const bf16x8*)&wdT[w * 16 + ln][lq * 8 + 32];
        #pragma unroll
        for (int tn = 0; tn < NT; ++tn) {
            const bf16x8 b0 = ldfrag8(&zsT[tn * 16 + ln][lq * 8]);
            const bf16x8 b1 = ldfrag8(&zsT[tn * 16 + ln][lq * 8 + 32]);
            acc[tn] = __builtin_amdgcn_mfma_f32_16x16x32_bf16(a0, b0, acc[tn], 0, 0, 0);
            acc[tn] = __builtin_amdgcn_mfma_f32_16x16x32_bf16(a1, b1, acc[tn], 0, 0, 0);
        }
    }

    // ---- epilogue: BN + residual + relu on C-frags, repack via ys=zsT ----
    __syncthreads();
    {
        const int c0 = w * 16 + lq * 4;   // C-frag rows c0..c0+3, col tn*16+ln
        float bb[4], ss[4], be[4];
        #pragma unroll
        for (int r = 0; r < 4; ++r) {
            bb[r] = bds[c0 + r]; ss[r] = scl[c0 + r]; be[r] = bet[c0 + r];
        }
        #pragma unroll
        for (int tn = 0; tn < NT; ++tn) {
            const int p = tn * 16 + ln;
            if (p < ROWS) {
                const uint2 u = *(const uint2*)&xsT[p][c0];
                const float rs[4] = {blo(u.x), bhi(u.x), blo(u.y), bhi(u.y)};
                float y[4];
                #pragma unroll
                for (int r = 0; r < 4; ++r)
                    y[r] = fmaxf((acc[tn][r] + bb[r]) * ss[r] + be[r] + rs[r], 0.f);
                uint2 pk;
                pk.x = (uint)f2bb(y[0]) | ((uint)f2bb(y[1]) << 16);
                pk.y = (uint)f2bb(y[2]) | ((uint)f2bb(y[3]) << 16);
                *(uint2*)&zsT[p][c0] = pk;   // ys[p][c]
            }
        }
    }
    __syncthreads();

    if constexpr (MODE == 0) {
        #pragma unroll
        for (int vv = 0; vv < 2; ++vv) {
            const int v = 2 * pj + vv;
            if (v < V) {
                #pragma unroll
                for (int r = 0; r < 4; ++r) {
                    const int c = ci * 4 + r;
                    const size_t base = (size_t)b * V * DD + (size_t)v * DD + c * TT + t0;
                    const ushort h0 = zsT[v * 4 + 0][c], h1 = zsT[v * 4 + 1][c];
                    const ushort h2 = zsT[v * 4 + 2][c], h3 = zsT[v * 4 + 3][c];
                    uint2 pk;
                    pk.x = (uint)h0 | ((uint)h1 << 16);
                    pk.y = (uint)h2 | ((uint)h3 << 16);
                    *(uint2*)&out_bf[base] = pk;
                }
            }
        }
    } else {
        const int v = pj;
        if (v < V) {
            #pragma unroll
            for (int r = 0; r < 4; ++r) {
                const int c = ci * 4 + r;
                const size_t base = (size_t)b * V * DD + (size_t)v * DD + c * TT + t0;
                const float4 o0 = *(const float4*)&Obuf[base];
                const float4 o1 = *(const float4*)&Obuf[base + 4];
                float4 y0, y1;
                y0.x = o0.x + b2f_us(zsT[v * 8 + 0][c]);
                y0.y = o0.y + b2f_us(zsT[v * 8 + 1][c]);
                y0.z = o0.z + b2f_us(zsT[v * 8 + 2][c]);
                y0.w = o0.w + b2f_us(zsT[v * 8 + 3][c]);
                y1.x = o1.x + b2f_us(zsT[v * 8 + 4][c]);
                y1.y = o1.y + b2f_us(zsT[v * 8 + 5][c]);
                y1.z = o1.z + b2f_us(zsT[v * 8 + 6][c]);
                y1.w = o1.w + b2f_us(zsT[v * 8 + 7][c]);
                *(float4*)&out_f[base] = y0;
                *(float4*)&out_f[base + 4] = y1;
            }
        }
    }
}

// ---------------------------------------------------------------------------
// attention (unchanged from round 4).
// ---------------------------------------------------------------------------
__global__ __launch_bounds__(256) void attn_kernel(const float* __restrict__ Q,
                                                   const bf16* __restrict__ Kg,
                                                   const bf16* __restrict__ Vg,
                                                   float* __restrict__ O) {
    int b = blockIdx.x, h = blockIdx.y, tid = threadIdx.x;
    __shared__ float qs[10 * DSH];
    __shared__ float ks[V1 * 321];
    __shared__ float att[10 * V1];
    const float* Qb = Q + (size_t)b * 10 * DD + h * DSH;
    for (int e = tid; e < 10 * DSH; e += 256) {
        int q = e / DSH, d = e % DSH;
        qs[e] = Qb[(size_t)q * DD + d];
    }
    const bf16* Kb = Kg + (size_t)b * V1 * DD + h * DSH;
    for (int e = tid; e < V1 * DSH; e += 256) {
        int kk = e / DSH, d = e % DSH;
        ks[kk * 321 + d] = b2f(Kb[(size_t)kk * DD + d]);
    }
    __syncthreads();
    const float scale = 0.019764235376052370f;  // 1/sqrt(2560)
    for (int e = tid; e < 10 * V1; e += 256) {
        int q = e / V1, kk = e % V1;
        float acc = 0.f;
        #pragma unroll 8
        for (int d = 0; d < DSH; ++d) acc += qs[q * DSH + d] * ks[kk * 321 + d];
        att[e] = acc * scale;
    }
    __syncthreads();
    if (tid < 10) {
        float mx = -1e30f;
        for (int k = 0; k < V1; ++k) mx = fmaxf(mx, att[tid * V1 + k]);
        float sum = 0.f;
        for (int k = 0; k < V1; ++k) {
            float e_ = expf(att[tid * V1 + k] - mx);
            att[tid * V1 + k] = e_;
            sum += e_;
        }
        float r = 1.0f / sum;
        for (int k = 0; k < V1; ++k) att[tid * V1 + k] *= r;
    }
    __syncthreads();
    const bf16* Vb = Vg + (size_t)b * V1 * DD + h * DSH;
    float* Ob = O + (size_t)b * 10 * DD + h * DSH;
    for (int hh = 0; hh < 2; ++hh) {
        for (int e = tid; e < V1 * 160; e += 256) {
            int kk = e / 160, dl = e % 160;
            ks[kk * 321 + dl] = b2f(Vb[(size_t)kk * DD + hh * 160 + dl]);
        }
        __syncthreads();
        for (int e = tid; e < 10 * 160; e += 256) {
            int q = e / 160, dl = e % 160;
            float acc = 0.f;
            #pragma unroll
            for (int k = 0; k < V1; ++k) acc += att[q * V1 + k] * ks[k * 321 + dl];
            Ob[(size_t)q * DD + hh * 160 + dl] = qs[q * DSH + hh * 160 + dl] + acc;
        }
        __syncthreads();
    }
}

// ---------------------------------------------------------------------------
extern "C" void kernel_launch(void* const* d_in, const int* in_sizes, int n_in,
                              void* d_out, int out_size, void* d_ws, size_t ws_size,
                              hipStream_t stream) {
    const float* Q = (const float*)d_in[0];
    const float* K = (const float*)d_in[1];
    const float* fck_PA = (const float*)d_in[2];
    const float* fck_Wa = (const float*)d_in[3];
    const float* fck_ba = (const float*)d_in[4];
    const float* fck_Wb = (const float*)d_in[5];
    const float* fck_bb = (const float*)d_in[6];
    const float* fck_Wd = (const float*)d_in[7];
    const float* fck_bd = (const float*)d_in[8];
    const float* fck_gamma = (const float*)d_in[9];
    const float* fck_beta = (const float*)d_in[10];
    const float* fcv_PA = (const float*)d_in[11];
    const float* fcv_Wa = (const float*)d_in[12];
    const float* fcv_ba = (const float*)d_in[13];
    const float* fcv_Wb = (const float*)d_in[14];
    const float* fcv_bb = (const float*)d_in[15];
    const float* fcv_Wd = (const float*)d_in[16];
    const float* fcv_bd = (const float*)d_in[17];
    const float* fcv_gamma = (const float*)d_in[18];
    const float* fcv_beta = (const float*)d_in[19];
    const float* fco_PA = (const float*)d_in[20];
    const float* fco_Wa = (const float*)d_in[21];
    const float* fco_ba = (const float*)d_in[22];
    const float* fco_Wb = (const float*)d_in[23];
    const float* fco_bb = (const float*)d_in[24];
    const float* fco_Wd = (const float*)d_in[25];
    const float* fco_bd = (const float*)d_in[26];
    const float* fco_gamma = (const float*)d_in[27];
    const float* fco_beta = (const float*)d_in[28];

    // Workspace (bytes), no overlaps, total ~95.9 MB (round-4 map).
    char* wsb = (char*)d_ws;
    bf16* Kg = (bf16*)(wsb);
    bf16* Vg = (bf16*)(wsb + 32768000);
    float* O = (float*)(wsb + 65536000);
    float* S1 = (float*)(wsb + 91750400);
    float* S2 = (float*)(wsb + 93670400);
    float* S3 = (float*)(wsb + 95590400);

    gcn_S2<V1, 2><<<dim3(BB, 3), dim3(256), 0, stream>>>(
        K, fck_Wa, fck_ba, fck_Wb, fck_bb, fck_PA, S1,
        fcv_Wa, fcv_ba, fcv_Wb, fcv_bb, fcv_PA, S2);

    gcn_apply3<V1, 4, 0><<<dim3(BB, 10), dim3(256), 0, stream>>>(
        K, S1, fck_Wd, fck_bd, fck_gamma, fck_beta, Kg, nullptr, nullptr);
    gcn_apply3<V1, 4, 0><<<dim3(BB, 10), dim3(256), 0, stream>>>(
        K, S2, fcv_Wd, fcv_bd, fcv_gamma, fcv_beta, Vg, nullptr, nullptr);

    attn_kernel<<<dim3(BB, NH), dim3(256), 0, stream>>>(Q, Kg, Vg, O);

    gcn_S2<V2, 1><<<dim3(BB, 3), dim3(256), 0, stream>>>(
        O, fco_Wa, fco_ba, fco_Wb, fco_bb, fco_PA, S3,
        nullptr, nullptr, nullptr, nullptr, nullptr, nullptr);

    gcn_apply3<V2, 8, 1><<<dim3(BB, 5), dim3(256), 0, stream>>>(
        O, S3, fco_Wd, fco_bd, fco_gamma, fco_beta, nullptr, (float*)d_out, O);
}

// Round 8
// 719.100 us; speedup vs baseline: 4.7109x; 1.2003x over previous
//
#include <hip/hip_runtime.h>
#include <hip/hip_bf16.h>

#define BB 256
#define CC 64
#define TT 40
#define DD 2560   // CC*TT
#define V1 25
#define V2 10
#define INTER 16
#define NH 8
#define DSH 320   // DD/NH

typedef __hip_bfloat16 bf16;
typedef unsigned int uint;
typedef unsigned short ushort;
typedef __attribute__((ext_vector_type(8))) short bf16x8;
typedef __attribute__((ext_vector_type(4))) float f32x4;

__device__ __forceinline__ float b2f(bf16 x) { return __bfloat162float(x); }

__device__ __forceinline__ ushort f2bb(float f) {
    uint x = __float_as_uint(f);
    uint r = x + 0x7fffu + ((x >> 16) & 1u);
    return (ushort)(r >> 16);
}
__device__ __forceinline__ float blo(uint u) { return __uint_as_float(u << 16); }
__device__ __forceinline__ float bhi(uint u) { return __uint_as_float(u & 0xffff0000u); }
__device__ __forceinline__ float b2f_us(ushort h) { return __uint_as_float(((uint)h) << 16); }
__device__ __forceinline__ uint4 pack8(const float* a) {
    uint4 pk;
    pk.x = (uint)f2bb(a[0]) | ((uint)f2bb(a[1]) << 16);
    pk.y = (uint)f2bb(a[2]) | ((uint)f2bb(a[3]) << 16);
    pk.z = (uint)f2bb(a[4]) | ((uint)f2bb(a[5]) << 16);
    pk.w = (uint)f2bb(a[6]) | ((uint)f2bb(a[7]) << 16);
    return pk;
}
__device__ __forceinline__ bf16x8 ldfrag8(const ushort* p) {
    union { bf16x8 v; uint2 u[2]; } t;
    t.u[0] = *(const uint2*)p;
    t.u[1] = *(const uint2*)(p + 4);
    return t.v;
}

// ---------------------------------------------------------------------------
// gcn_S3 (V=25, fck+fcv fused): grid = (tc*256 + b), 1280 blocks.
// Per block: stage x chunk (8 t's of all v,c) once; for each subset s:
//   proj (MFMA): [Wa0;Wb0;Wa1;Wb1](64x64) @ xsT(64x200) -> abT in Gram layout
//   Gram (MFMA): M_part[v][vp] = sum_k abT_a[v][k] * abT_b[vp][k], k=(j,tl)=128
// Partial Grams written to Mpart[tc][b][s*2+np][625]; reduce kernel sums+softmax.
// MFMA fragment mapping (verified by apply3): A/B-frag dim16=lane&15,
// k=(lane>>4)*8+i; C-frag row=(lane>>4)*4+reg, col=lane&15.
// ---------------------------------------------------------------------------
__global__ __launch_bounds__(256) void gcn_S3(
    const float* __restrict__ X,
    const float* __restrict__ Wa0, const float* __restrict__ ba0,
    const float* __restrict__ Wb0, const float* __restrict__ bb0,
    const float* __restrict__ Wa1, const float* __restrict__ ba1,
    const float* __restrict__ Wb1, const float* __restrict__ bb1,
    float* __restrict__ Mpart) {
    __shared__ ushort xsT[208][72];    // [p=v*8+tl][c]; rows 200..207 garbage
    __shared__ ushort wT[64][72];      // [mat*16+j][c] for current s
    __shared__ ushort abT[4][32][136]; // [mat][v][j*8+tl]
    __shared__ float biasS[64];

    const int tid = threadIdx.x;
    const int b = blockIdx.x & 255, tc = blockIdx.x >> 8;
    const int t0 = tc * 8;
    const int lane = tid & 63, w = tid >> 6;
    const int ln = lane & 15, lq = lane >> 4;

    // stage x chunk: (v,c) -> 8 t's, bf16 into transposed rows p=v*8+tl
    const float* Xb = X + (size_t)b * V1 * DD;
    for (int e = tid; e < V1 * 64; e += 256) {
        const int v = e >> 6, c = e & 63;
        const float* src = Xb + (size_t)v * DD + c * TT + t0;
        const float4 f0 = *(const float4*)src;
        const float4 f1 = *(const float4*)(src + 4);
        const float tmp[8] = {f0.x, f0.y, f0.z, f0.w, f1.x, f1.y, f1.z, f1.w};
        #pragma unroll
        for (int tl = 0; tl < 8; ++tl) xsT[v * 8 + tl][c] = f2bb(tmp[tl]);
    }

    for (int s = 0; s < 3; ++s) {
        if (s) __syncthreads();        // prev Gram done with abT, proj done with wT
        // stage W (4 mats x 16 x 64) + bias for this s
        for (int e = tid; e < 4096; e += 256) {
            const int mat = e >> 10, r = e & 1023;
            const float* Wp = (mat == 0) ? Wa0 : (mat == 1) ? Wb0 : (mat == 2) ? Wa1 : Wb1;
            wT[(mat << 4) + (r >> 6)][r & 63] = f2bb(Wp[s * 1024 + r]);
        }
        if (tid < 64) {
            const int mat = tid >> 4, j = tid & 15;
            const float* bp = (mat == 0) ? ba0 : (mat == 1) ? bb0 : (mat == 2) ? ba1 : bb1;
            biasS[tid] = bp[s * 16 + j];
        }
        __syncthreads();               // wT/xsT ready

        // ---- projection: wave w computes mat w over 13 n-tiles ----
        const bf16x8 a0 = *(const bf16x8*)&wT[w * 16 + ln][lq * 8];
        const bf16x8 a1 = *(const bf16x8*)&wT[w * 16 + ln][lq * 8 + 32];
        float br[4];
        #pragma unroll
        for (int r = 0; r < 4; ++r) br[r] = biasS[w * 16 + lq * 4 + r];
        for (int nt = 0; nt < 13; ++nt) {
            const bf16x8 b0 = *(const bf16x8*)&xsT[nt * 16 + ln][lq * 8];
            const bf16x8 b1 = *(const bf16x8*)&xsT[nt * 16 + ln][lq * 8 + 32];
            f32x4 acc = (f32x4){0.f, 0.f, 0.f, 0.f};
            acc = __builtin_amdgcn_mfma_f32_16x16x32_bf16(a0, b0, acc, 0, 0, 0);
            acc = __builtin_amdgcn_mfma_f32_16x16x32_bf16(a1, b1, acc, 0, 0, 0);
            const int p = nt * 16 + ln;
            if (p < 200) {
                const int v = p >> 3, tl = p & 7;
                #pragma unroll
                for (int r = 0; r < 4; ++r)
                    abT[w][v][(lq * 4 + r) * 8 + tl] = f2bb(acc[r] + br[r]);
            }
        }
        __syncthreads();               // abT ready

        // ---- Gram: 8 tile-units (np,mt,nt), wave w does units w and w+4 ----
        #pragma unroll
        for (int uu = 0; uu < 2; ++uu) {
            const int u = w + uu * 4;
            const int np = u >> 2, mt = (u >> 1) & 1, ntl = u & 1;
            const ushort* Ap = &abT[np * 2 + 0][mt * 16 + ln][lq * 8];
            const ushort* Bp = &abT[np * 2 + 1][ntl * 16 + ln][lq * 8];
            f32x4 g = (f32x4){0.f, 0.f, 0.f, 0.f};
            g = __builtin_amdgcn_mfma_f32_16x16x32_bf16(
                    *(const bf16x8*)Ap, *(const bf16x8*)Bp, g, 0, 0, 0);
            g = __builtin_amdgcn_mfma_f32_16x16x32_bf16(
                    *(const bf16x8*)(Ap + 32), *(const bf16x8*)(Bp + 32), g, 0, 0, 0);
            g = __builtin_amdgcn_mfma_f32_16x16x32_bf16(
                    *(const bf16x8*)(Ap + 64), *(const bf16x8*)(Bp + 64), g, 0, 0, 0);
            g = __builtin_amdgcn_mfma_f32_16x16x32_bf16(
                    *(const bf16x8*)(Ap + 96), *(const bf16x8*)(Bp + 96), g, 0, 0, 0);
            const int vp = ntl * 16 + ln;
            if (vp < V1) {
                float* Mb = Mpart + (((size_t)tc * 256 + b) * 6 + (s * 2 + np)) * 625;
                #pragma unroll
                for (int r = 0; r < 4; ++r) {
                    const int v = mt * 16 + lq * 4 + r;
                    if (v < V1) Mb[v * V1 + vp] = g[r];
                }
            }
        }
    }
}

// ---------------------------------------------------------------------------
// reduce_softmax: grid (b, snp=s*2+np). Sum 5 chunk-partials, column softmax
// over v (axis=-2), + PA, write S (B,3,25,25).
// ---------------------------------------------------------------------------
__global__ __launch_bounds__(128) void reduce_softmax(
    const float* __restrict__ Mpart,
    const float* __restrict__ PA0, const float* __restrict__ PA1,
    float* __restrict__ S1out, float* __restrict__ S2out) {
    __shared__ float Ms[625];
    const int tid = threadIdx.x, b = blockIdx.x, snp = blockIdx.y;
    const int s = snp >> 1, np = snp & 1;
    for (int e = tid; e < 625; e += 128) {
        float sum = 0.f;
        #pragma unroll
        for (int tcc = 0; tcc < 5; ++tcc)
            sum += Mpart[(((size_t)tcc * 256 + b) * 6 + snp) * 625 + e];
        Ms[e] = sum;
    }
    __syncthreads();
    if (tid < V1) {
        const int vp = tid;
        const float invIT = 1.0f / 640.0f;
        float mx = -1e30f;
        for (int v = 0; v < V1; ++v) mx = fmaxf(mx, Ms[v * V1 + vp]);
        float sum = 0.f;
        for (int v = 0; v < V1; ++v) sum += expf((Ms[v * V1 + vp] - mx) * invIT);
        const float rs = 1.f / sum;
        const float* PAn = np ? PA1 : PA0;
        float* Sn = np ? S2out : S1out;
        for (int v = 0; v < V1; ++v) {
            const float e_ = expf((Ms[v * V1 + vp] - mx) * invIT);
            Sn[((size_t)(b * 3 + s) * V1 + v) * V1 + vp] =
                e_ * rs + PAn[(s * V1 + v) * V1 + vp];
        }
    }
}

// ---------------------------------------------------------------------------
// gcn_S2 (VALU version, kept for the small V=10 fco case).
// ---------------------------------------------------------------------------
template<int V, int NP>
__global__ __launch_bounds__(256) void gcn_S2(
    const float* __restrict__ X,
    const float* __restrict__ Wa0, const float* __restrict__ ba0,
    const float* __restrict__ Wb0, const float* __restrict__ bb0,
    const float* __restrict__ PA0, float* __restrict__ Sout0,
    const float* __restrict__ Wa1, const float* __restrict__ ba1,
    const float* __restrict__ Wb1, const float* __restrict__ bb1,
    const float* __restrict__ PA1, float* __restrict__ Sout1) {
    constexpr int TC = 8;
    constexpr int NCH = TT / TC;
    constexpr int P = V * TC;
    constexpr int ROWS = NP * 32;
    constexpr int NRQ = ROWS / 4;
    constexpr int NC8 = P / 8;
    constexpr int NTILE = NRQ * NC8;
    constexpr int NM = NP * V * V;
    constexpr int NMI = (NM + 255) / 256;

    __shared__ ushort xs[64][P];
    __shared__ ushort ab[ROWS][P];
    __shared__ ushort wT[64][ROWS];
    __shared__ float biasL[ROWS];
    __shared__ float M[NM];

    const int tid = threadIdx.x, b = blockIdx.x, s = blockIdx.y;

    for (int e = tid; e < 16 * 64; e += 256) {
        int c = e & 63;
        int j = e >> 6;
        wT[c][j]      = f2bb(Wa0[s * 1024 + e]);
        wT[c][16 + j] = f2bb(Wb0[s * 1024 + e]);
        if constexpr (NP == 2) {
            wT[c][32 + j] = f2bb(Wa1[s * 1024 + e]);
            wT[c][48 + j] = f2bb(Wb1[s * 1024 + e]);
        }
    }
    if (tid < 16) {
        biasL[tid]      = ba0[s * 16 + tid];
        biasL[16 + tid] = bb0[s * 16 + tid];
        if constexpr (NP == 2) {
            biasL[32 + tid] = ba1[s * 16 + tid];
            biasL[48 + tid] = bb1[s * 16 + tid];
        }
    }

    float macc[NMI];
    #pragma unroll
    for (int k = 0; k < NMI; ++k) macc[k] = 0.f;

    const float* Xb = X + (size_t)b * V * DD;
    for (int tc = 0; tc < NCH; ++tc) {
        const int t0 = tc * TC;
        for (int e = tid; e < V * 64; e += 256) {
            const int v = e >> 6, c = e & 63;
            const float* src = Xb + (size_t)v * DD + c * TT + t0;
            const float4 f0 = *(const float4*)src;
            const float4 f1 = *(const float4*)(src + 4);
            const float tmp[8] = {f0.x, f0.y, f0.z, f0.w, f1.x, f1.y, f1.z, f1.w};
            *(uint4*)&xs[c][v * 8] = pack8(tmp);
        }
        __syncthreads();
        for (int tau = tid; tau < NTILE; tau += 256) {
            const int rq = tau % NRQ, co = tau / NRQ;
            float acc[4][8];
            #pragma unroll
            for (int r = 0; r < 4; ++r) {
                const float bv = biasL[4 * rq + r];
                #pragma unroll
                for (int cc = 0; cc < 8; ++cc) acc[r][cc] = bv;
            }
            for (int c = 0; c < 64; ++c) {
                const uint2 wv = *(const uint2*)&wT[c][4 * rq];
                const uint4 xv = *(const uint4*)&xs[c][8 * co];
                const float w0 = blo(wv.x), w1 = bhi(wv.x);
                const float w2 = blo(wv.y), w3 = bhi(wv.y);
                const float x0 = blo(xv.x), x1 = bhi(xv.x);
                const float x2 = blo(xv.y), x3 = bhi(xv.y);
                const float x4 = blo(xv.z), x5 = bhi(xv.z);
                const float x6 = blo(xv.w), x7 = bhi(xv.w);
                acc[0][0] += w0 * x0; acc[0][1] += w0 * x1;
                acc[0][2] += w0 * x2; acc[0][3] += w0 * x3;
                acc[0][4] += w0 * x4; acc[0][5] += w0 * x5;
                acc[0][6] += w0 * x6; acc[0][7] += w0 * x7;
                acc[1][0] += w1 * x0; acc[1][1] += w1 * x1;
                acc[1][2] += w1 * x2; acc[1][3] += w1 * x3;
                acc[1][4] += w1 * x4; acc[1][5] += w1 * x5;
                acc[1][6] += w1 * x6; acc[1][7] += w1 * x7;
                acc[2][0] += w2 * x0; acc[2][1] += w2 * x1;
                acc[2][2] += w2 * x2; acc[2][3] += w2 * x3;
                acc[2][4] += w2 * x4; acc[2][5] += w2 * x5;
                acc[2][6] += w2 * x6; acc[2][7] += w2 * x7;
                acc[3][0] += w3 * x0; acc[3][1] += w3 * x1;
                acc[3][2] += w3 * x2; acc[3][3] += w3 * x3;
                acc[3][4] += w3 * x4; acc[3][5] += w3 * x5;
                acc[3][6] += w3 * x6; acc[3][7] += w3 * x7;
            }
            #pragma unroll
            for (int r = 0; r < 4; ++r)
                *(uint4*)&ab[4 * rq + r][8 * co] = pack8(acc[r]);
        }
        __syncthreads();
        #pragma unroll
        for (int k = 0; k < NMI; ++k) {
            const int idx = tid + k * 256;
            if (idx < NM) {
                const int np = idx / (V * V), r = idx % (V * V);
                const int v = r / V, vp = r % V;
                const int ra = np * 32, rb = np * 32 + 16;
                float mm = 0.f;
                #pragma unroll
                for (int j = 0; j < 16; ++j) {
                    const uint4 av = *(const uint4*)&ab[ra + j][v * 8];
                    const uint4 bv = *(const uint4*)&ab[rb + j][vp * 8];
                    mm += blo(av.x) * blo(bv.x) + bhi(av.x) * bhi(bv.x)
                        + blo(av.y) * blo(bv.y) + bhi(av.y) * bhi(bv.y)
                        + blo(av.z) * blo(bv.z) + bhi(av.z) * bhi(bv.z)
                        + blo(av.w) * blo(bv.w) + bhi(av.w) * bhi(bv.w);
                }
                macc[k] += mm;
            }
        }
    }

    #pragma unroll
    for (int k = 0; k < NMI; ++k) {
        const int idx = tid + k * 256;
        if (idx < NM) M[idx] = macc[k];
    }
    __syncthreads();

    const float invIT = 1.0f / 640.0f;
    if (tid < NP * V) {
        const int np = tid / V, vp = tid % V;
        const float* Mn = &M[np * V * V];
        float mx = -1e30f;
        for (int v = 0; v < V; ++v) mx = fmaxf(mx, Mn[v * V + vp]);
        float sum = 0.f;
        for (int v = 0; v < V; ++v) sum += expf((Mn[v * V + vp] - mx) * invIT);
        const float rs = 1.f / sum;
        const float* PAn = (np == 0) ? PA0 : PA1;
        float* Sn = (np == 0) ? Sout0 : Sout1;
        for (int v = 0; v < V; ++v) {
            const float e_ = expf((Mn[v * V + vp] - mx) * invIT);
            Sn[((size_t)(b * 3 + s) * V + v) * V + vp] =
                e_ * rs + PAn[(s * V + v) * V + vp];
        }
    }
}

// ---------------------------------------------------------------------------
// gcn_apply3: register GEMM-1 + MFMA GEMM-2 (unchanged from round 7).
// ---------------------------------------------------------------------------
template<int V, int TC, int MODE>
__global__ __launch_bounds__(256) void gcn_apply3(const float* __restrict__ X,
                                                  const float* __restrict__ Sbuf,
                                                  const float* __restrict__ Wd,
                                                  const float* __restrict__ bd,
                                                  const float* __restrict__ gamma,
                                                  const float* __restrict__ beta,
                                                  bf16* __restrict__ out_bf,
                                                  float* __restrict__ out_f,
                                                  const float* __restrict__ Obuf) {
    constexpr int VSLOT = 128 / TC;
    constexpr int ROWS = V * TC;
    constexpr int NT = (V == 25) ? 7 : 5;

    __shared__ ushort xsT[ROWS][68];
    __shared__ ushort zsT[128][68];
    __shared__ ushort wdT[64][72];
    __shared__ ushort Sl[3][VSLOT][34];
    __shared__ float bds[64], scl[64], bet[64];

    const int tid = threadIdx.x, b = blockIdx.x, chunk = blockIdx.y;
    const int ci = tid >> 4, pj = tid & 15;
    const int lane = tid & 63, w = tid >> 6;
    const int ln = lane & 15, lq = lane >> 4;
    const int t0 = chunk * TC;

    for (int e = tid; e < 3 * VSLOT * 17; e += 256) ((uint*)Sl)[e] = 0u;
    if (tid < 64) {
        bds[tid] = bd[tid] + bd[64 + tid] + bd[128 + tid];
        scl[tid] = gamma[tid] * rsqrtf(1.f + 1e-5f);
        bet[tid] = beta[tid];
    }
    __syncthreads();
    for (int e = tid; e < 3 * V * V; e += 256) {
        int s = e / (V * V), r = e % (V * V);
        Sl[s][r / V][r % V] = f2bb(Sbuf[(size_t)b * 3 * V * V + e]);
    }
    const float* Xb = X + (size_t)b * V * DD;
    for (int e = tid; e < V * 64 * TC; e += 256) {
        int v = e / (64 * TC), inner = e % (64 * TC);
        int c = inner / TC, tl = inner % TC;
        xsT[v * TC + tl][c] = f2bb(Xb[(size_t)v * DD + c * TT + t0 + tl]);
    }
    __syncthreads();

    f32x4 acc[NT];
    #pragma unroll
    for (int tn = 0; tn < NT; ++tn) acc[tn] = (f32x4){0.f, 0.f, 0.f, 0.f};

    for (int s = 0; s < 3; ++s) {
        if (s) __syncthreads();
        for (int e = tid; e < 4096; e += 256)
            wdT[e >> 6][e & 63] = f2bb(Wd[s * 4096 + e]);

        float za[4][8];
        #pragma unroll
        for (int r = 0; r < 4; ++r)
            #pragma unroll
            for (int cc = 0; cc < 8; ++cc) za[r][cc] = 0.f;

        if constexpr (V == 25) {
            for (int v0 = 0; v0 < 25; ++v0) {
                const uint sv = *(const uint*)&Sl[s][v0][2 * pj];
                const float svx = blo(sv), svy = bhi(sv);
                #pragma unroll
                for (int tl = 0; tl < 4; ++tl) {
                    const uint2 u = *(const uint2*)&xsT[v0 * 4 + tl][ci * 4];
                    const float a0 = blo(u.x), a1 = bhi(u.x);
                    const float a2 = blo(u.y), a3 = bhi(u.y);
                    za[0][tl] += a0 * svx;  za[0][4 + tl] += a0 * svy;
                    za[1][tl] += a1 * svx;  za[1][4 + tl] += a1 * svy;
                    za[2][tl] += a2 * svx;  za[2][4 + tl] += a2 * svy;
                    za[3][tl] += a3 * svx;  za[3][4 + tl] += a3 * svy;
                }
            }
        } else {
            for (int v0 = 0; v0 < 10; ++v0) {
                const float sv = b2f_us(Sl[s][v0][pj]);
                #pragma unroll
                for (int tl = 0; tl < 8; ++tl) {
                    const uint2 u = *(const uint2*)&xsT[v0 * 8 + tl][ci * 4];
                    za[0][tl] += blo(u.x) * sv;
                    za[1][tl] += bhi(u.x) * sv;
                    za[2][tl] += blo(u.y) * sv;
                    za[3][tl] += bhi(u.y) * sv;
                }
            }
        }
        #pragma unroll
        for (int cc = 0; cc < 8; ++cc) {
            uint2 pk;
            pk.x = (uint)f2bb(za[0][cc]) | ((uint)f2bb(za[1][cc]) << 16);
            pk.y = (uint)f2bb(za[2][cc]) | ((uint)f2bb(za[3][cc]) << 16);
            *(uint2*)&zsT[pj * 8 + cc][ci * 4] = pk;
        }
        __syncthreads();

        const bf16x8 a0 = *(const bf16x8*)&wdT[w * 16 + ln][lq * 8];
        const bf16x8 a1 = *(const bf16x8*)&wdT[w * 16 + ln][lq * 8 + 32];
        #pragma unroll
        for (int tn = 0; tn < NT; ++tn) {
            const bf16x8 b0 = ldfrag8(&zsT[tn * 16 + ln][lq * 8]);
            const bf16x8 b1 = ldfrag8(&zsT[tn * 16 + ln][lq * 8 + 32]);
            acc[tn] = __builtin_amdgcn_mfma_f32_16x16x32_bf16(a0, b0, acc[tn], 0, 0, 0);
            acc[tn] = __builtin_amdgcn_mfma_f32_16x16x32_bf16(a1, b1, acc[tn], 0, 0, 0);
        }
    }

    __syncthreads();
    {
        const int c0 = w * 16 + lq * 4;
        float bb[4], ss[4], be[4];
        #pragma unroll
        for (int r = 0; r < 4; ++r) {
            bb[r] = bds[c0 + r]; ss[r] = scl[c0 + r]; be[r] = bet[c0 + r];
        }
        #pragma unroll
        for (int tn = 0; tn < NT; ++tn) {
            const int p = tn * 16 + ln;
            if (p < ROWS) {
                const uint2 u = *(const uint2*)&xsT[p][c0];
                const float rs[4] = {blo(u.x), bhi(u.x), blo(u.y), bhi(u.y)};
                float y[4];
                #pragma unroll
                for (int r = 0; r < 4; ++r)
                    y[r] = fmaxf((acc[tn][r] + bb[r]) * ss[r] + be[r] + rs[r], 0.f);
                uint2 pk;
                pk.x = (uint)f2bb(y[0]) | ((uint)f2bb(y[1]) << 16);
                pk.y = (uint)f2bb(y[2]) | ((uint)f2bb(y[3]) << 16);
                *(uint2*)&zsT[p][c0] = pk;
            }
        }
    }
    __syncthreads();

    if constexpr (MODE == 0) {
        #pragma unroll
        for (int vv = 0; vv < 2; ++vv) {
            const int v = 2 * pj + vv;
            if (v < V) {
                #pragma unroll
                for (int r = 0; r < 4; ++r) {
                    const int c = ci * 4 + r;
                    const size_t base = (size_t)b * V * DD + (size_t)v * DD + c * TT + t0;
                    const ushort h0 = zsT[v * 4 + 0][c], h1 = zsT[v * 4 + 1][c];
                    const ushort h2 = zsT[v * 4 + 2][c], h3 = zsT[v * 4 + 3][c];
                    uint2 pk;
                    pk.x = (uint)h0 | ((uint)h1 << 16);
                    pk.y = (uint)h2 | ((uint)h3 << 16);
                    *(uint2*)&out_bf[base] = pk;
                }
            }
        }
    } else {
        const int v = pj;
        if (v < V) {
            #pragma unroll
            for (int r = 0; r < 4; ++r) {
                const int c = ci * 4 + r;
                const size_t base = (size_t)b * V * DD + (size_t)v * DD + c * TT + t0;
                const float4 o0 = *(const float4*)&Obuf[base];
                const float4 o1 = *(const float4*)&Obuf[base + 4];
                float4 y0, y1;
                y0.x = o0.x + b2f_us(zsT[v * 8 + 0][c]);
                y0.y = o0.y + b2f_us(zsT[v * 8 + 1][c]);
                y0.z = o0.z + b2f_us(zsT[v * 8 + 2][c]);
                y0.w = o0.w + b2f_us(zsT[v * 8 + 3][c]);
                y1.x = o1.x + b2f_us(zsT[v * 8 + 4][c]);
                y1.y = o1.y + b2f_us(zsT[v * 8 + 5][c]);
                y1.z = o1.z + b2f_us(zsT[v * 8 + 6][c]);
                y1.w = o1.w + b2f_us(zsT[v * 8 + 7][c]);
                *(float4*)&out_f[base] = y0;
                *(float4*)&out_f[base + 4] = y1;
            }
        }
    }
}

// ---------------------------------------------------------------------------
// attention (unchanged).
// ---------------------------------------------------------------------------
__global__ __launch_bounds__(256) void attn_kernel(const float* __restrict__ Q,
                                                   const bf16* __restrict__ Kg,
                                                   const bf16* __restrict__ Vg,
                                                   float* __restrict__ O) {
    int b = blockIdx.x, h = blockIdx.y, tid = threadIdx.x;
    __shared__ float qs[10 * DSH];
    __shared__ float ks[V1 * 321];
    __shared__ float att[10 * V1];
    const float* Qb = Q + (size_t)b * 10 * DD + h * DSH;
    for (int e = tid; e < 10 * DSH; e += 256) {
        int q = e / DSH, d = e % DSH;
        qs[e] = Qb[(size_t)q * DD + d];
    }
    const bf16* Kb = Kg + (size_t)b * V1 * DD + h * DSH;
    for (int e = tid; e < V1 * DSH; e += 256) {
        int kk = e / DSH, d = e % DSH;
        ks[kk * 321 + d] = b2f(Kb[(size_t)kk * DD + d]);
    }
    __syncthreads();
    const float scale = 0.019764235376052370f;  // 1/sqrt(2560)
    for (int e = tid; e < 10 * V1; e += 256) {
        int q = e / V1, kk = e % V1;
        float acc = 0.f;
        #pragma unroll 8
        for (int d = 0; d < DSH; ++d) acc += qs[q * DSH + d] * ks[kk * 321 + d];
        att[e] = acc * scale;
    }
    __syncthreads();
    if (tid < 10) {
        float mx = -1e30f;
        for (int k = 0; k < V1; ++k) mx = fmaxf(mx, att[tid * V1 + k]);
        float sum = 0.f;
        for (int k = 0; k < V1; ++k) {
            float e_ = expf(att[tid * V1 + k] - mx);
            att[tid * V1 + k] = e_;
            sum += e_;
        }
        float r = 1.0f / sum;
        for (int k = 0; k < V1; ++k) att[tid * V1 + k] *= r;
    }
    __syncthreads();
    const bf16* Vb = Vg + (size_t)b * V1 * DD + h * DSH;
    float* Ob = O + (size_t)b * 10 * DD + h * DSH;
    for (int hh = 0; hh < 2; ++hh) {
        for (int e = tid; e < V1 * 160; e += 256) {
            int kk = e / 160, dl = e % 160;
            ks[kk * 321 + dl] = b2f(Vb[(size_t)kk * DD + hh * 160 + dl]);
        }
        __syncthreads();
        for (int e = tid; e < 10 * 160; e += 256) {
            int q = e / 160, dl = e % 160;
            float acc = 0.f;
            #pragma unroll
            for (int k = 0; k < V1; ++k) acc += att[q * V1 + k] * ks[k * 321 + dl];
            Ob[(size_t)q * DD + hh * 160 + dl] = qs[q * DSH + hh * 160 + dl] + acc;
        }
        __syncthreads();
    }
}

// ---------------------------------------------------------------------------
extern "C" void kernel_launch(void* const* d_in, const int* in_sizes, int n_in,
                              void* d_out, int out_size, void* d_ws, size_t ws_size,
                              hipStream_t stream) {
    const float* Q = (const float*)d_in[0];
    const float* K = (const float*)d_in[1];
    const float* fck_PA = (const float*)d_in[2];
    const float* fck_Wa = (const float*)d_in[3];
    const float* fck_ba = (const float*)d_in[4];
    const float* fck_Wb = (const float*)d_in[5];
    const float* fck_bb = (const float*)d_in[6];
    const float* fck_Wd = (const float*)d_in[7];
    const float* fck_bd = (const float*)d_in[8];
    const float* fck_gamma = (const float*)d_in[9];
    const float* fck_beta = (const float*)d_in[10];
    const float* fcv_PA = (const float*)d_in[11];
    const float* fcv_Wa = (const float*)d_in[12];
    const float* fcv_ba = (const float*)d_in[13];
    const float* fcv_Wb = (const float*)d_in[14];
    const float* fcv_bb = (const float*)d_in[15];
    const float* fcv_Wd = (const float*)d_in[16];
    const float* fcv_bd = (const float*)d_in[17];
    const float* fcv_gamma = (const float*)d_in[18];
    const float* fcv_beta = (const float*)d_in[19];
    const float* fco_PA = (const float*)d_in[20];
    const float* fco_Wa = (const float*)d_in[21];
    const float* fco_ba = (const float*)d_in[22];
    const float* fco_Wb = (const float*)d_in[23];
    const float* fco_bb = (const float*)d_in[24];
    const float* fco_Wd = (const float*)d_in[25];
    const float* fco_bd = (const float*)d_in[26];
    const float* fco_gamma = (const float*)d_in[27];
    const float* fco_beta = (const float*)d_in[28];

    // Workspace (round-4 map). Mpart (19.2 MB) aliases the Kg region: its
    // lifetime (gcn_S3 -> reduce_softmax) ends before apply3 writes Kg.
    char* wsb = (char*)d_ws;
    bf16* Kg = (bf16*)(wsb);
    bf16* Vg = (bf16*)(wsb + 32768000);
    float* O = (float*)(wsb + 65536000);
    float* S1 = (float*)(wsb + 91750400);
    float* S2 = (float*)(wsb + 93670400);
    float* S3 = (float*)(wsb + 95590400);
    float* Mpart = (float*)(wsb);   // [5][256][6][625] fp32 = 19.2 MB

    gcn_S3<<<dim3(BB * 5), dim3(256), 0, stream>>>(
        K, fck_Wa, fck_ba, fck_Wb, fck_bb,
        fcv_Wa, fcv_ba, fcv_Wb, fcv_bb, Mpart);

    reduce_softmax<<<dim3(BB, 6), dim3(128), 0, stream>>>(
        Mpart, fck_PA, fcv_PA, S1, S2);

    gcn_apply3<V1, 4, 0><<<dim3(BB, 10), dim3(256), 0, stream>>>(
        K, S1, fck_Wd, fck_bd, fck_gamma, fck_beta, Kg, nullptr, nullptr);
    gcn_apply3<V1, 4, 0><<<dim3(BB, 10), dim3(256), 0, stream>>>(
        K, S2, fcv_Wd, fcv_bd, fcv_gamma, fcv_beta, Vg, nullptr, nullptr);

    attn_kernel<<<dim3(BB, NH), dim3(256), 0, stream>>>(Q, Kg, Vg, O);

    gcn_S2<V2, 1><<<dim3(BB, 3), dim3(256), 0, stream>>>(
        O, fco_Wa, fco_ba, fco_Wb, fco_bb, fco_PA, S3,
        nullptr, nullptr, nullptr, nullptr, nullptr, nullptr);

    gcn_apply3<V2, 8, 1><<<dim3(BB, 5), dim3(256), 0, stream>>>(
        O, S3, fco_Wd, fco_bd, fco_gamma, fco_beta, nullptr, (float*)d_out, O);
}